// Round 2
// baseline (9426.818 us; speedup 1.0000x reference)
//
#include <hip/hip_runtime.h>
#include <cmath>

#define LEAK 0.2f
#define BN_EPS 1e-5f

static inline int cdiv(long long a, long long b){ return (int)((a + b - 1) / b); }

// ---- bf16 helpers (manual, RNE) -------------------------------------------
__device__ __forceinline__ float bf2f(unsigned short u){
    return __uint_as_float(((unsigned int)u) << 16);
}
__device__ __forceinline__ unsigned short f2bf(float f){
    unsigned int u = __float_as_uint(f);
    u += 0x7FFFu + ((u >> 16) & 1u);
    return (unsigned short)(u >> 16);
}
__device__ __forceinline__ float ldA(const float* p){ return *p; }
__device__ __forceinline__ float ldA(const unsigned short* p){ return bf2f(*p); }
__device__ __forceinline__ void stC(float* p, float v){ *p = v; }
__device__ __forceinline__ void stC(unsigned short* p, float v){ *p = f2bf(v); }

// ---------------------------------------------------------------------------
// Tiled GEMM: C[M,Nc] (+)= A[M,K] @ B[K,Nc] (+bias, optional relu)
// A: fp32 or bf16(ushort); B: fp32; C: fp32 or bf16. K % 16 == 0.
// ---------------------------------------------------------------------------
template<typename TA, typename TC, bool ACC, bool RELU>
__global__ __launch_bounds__(256) void gemm_t(
    const TA* __restrict__ A, const float* __restrict__ B,
    const float* __restrict__ bias, TC* __restrict__ C,
    int M, int K, int Nc, int lda, int ldb, int ldc)
{
    __shared__ float As[16][65];
    __shared__ float Bs[16][64];
    const int tid = threadIdx.x;
    const int tx = tid & 15, ty = tid >> 4;
    const int row0 = blockIdx.y * 64, col0 = blockIdx.x * 64;
    float acc[4][4] = {};

    for (int k0 = 0; k0 < K; k0 += 16) {
        #pragma unroll
        for (int i = 0; i < 4; ++i) {
            int f = tid * 4 + i, r = f >> 4, c = f & 15;
            int gr = row0 + r;
            As[c][r] = (gr < M) ? ldA(&A[(size_t)gr * lda + k0 + c]) : 0.f;
        }
        #pragma unroll
        for (int i = 0; i < 4; ++i) {
            int f = tid * 4 + i, r = f >> 6, c = f & 63;
            int gc = col0 + c;
            Bs[r][c] = (gc < Nc) ? B[(size_t)(k0 + r) * ldb + gc] : 0.f;
        }
        __syncthreads();
        #pragma unroll
        for (int kk = 0; kk < 16; ++kk) {
            float a[4], b[4];
            #pragma unroll
            for (int i = 0; i < 4; ++i) a[i] = As[kk][ty + 16 * i];
            #pragma unroll
            for (int j = 0; j < 4; ++j) b[j] = Bs[kk][tx + 16 * j];
            #pragma unroll
            for (int i = 0; i < 4; ++i)
                #pragma unroll
                for (int j = 0; j < 4; ++j)
                    acc[i][j] += a[i] * b[j];
        }
        __syncthreads();
    }
    #pragma unroll
    for (int i = 0; i < 4; ++i) {
        int r = row0 + ty + 16 * i;
        if (r >= M) continue;
        #pragma unroll
        for (int j = 0; j < 4; ++j) {
            int c = col0 + tx + 16 * j;
            if (c >= Nc) continue;
            float v = acc[i][j];
            if (bias) v += bias[c];
            if constexpr (ACC) v += reinterpret_cast<const float*>(C)[(size_t)r * ldc + c];
            if constexpr (RELU) v = fmaxf(v, 0.f);
            stC(&C[(size_t)r * ldc + c], v);
        }
    }
}

// ---- attention logits, single head: wave per node --------------------------
__global__ void attn_logits1(const unsigned short* __restrict__ h,
                             const float* __restrict__ avs, const float* __restrict__ avd,
                             float* __restrict__ als, float* __restrict__ ald, int N, int C)
{
    int w = (int)(((long long)blockIdx.x * blockDim.x + threadIdx.x) >> 6);
    int lane = threadIdx.x & 63;
    if (w >= N) return;
    const unsigned short* hp = h + (size_t)w * C;
    float s = 0.f, d = 0.f;
    for (int c = lane; c < C; c += 64) {
        float v = bf2f(hp[c]);
        s += v * avs[c];
        d += v * avd[c];
    }
    #pragma unroll
    for (int off = 32; off; off >>= 1) {
        s += __shfl_down(s, off);
        d += __shfl_down(d, off);
    }
    if (lane == 0) { als[w] = s; ald[w] = d; }
}

__device__ __forceinline__ int e_src(const int* es, int E, int k){ return k < E ? es[k] : k - E; }
__device__ __forceinline__ int e_dst(const int* ed, int E, int k){ return k < E ? ed[k] : k - E; }

__global__ void gat_edge_a1(const int* __restrict__ es, const int* __restrict__ ed,
                            int E, int Etot, const float* __restrict__ als,
                            const float* __restrict__ ald,
                            float* __restrict__ ex, float* __restrict__ ssum)
{
    int k = blockIdx.x * blockDim.x + threadIdx.x;
    if (k >= Etot) return;
    int sn = e_src(es, E, k), dn = e_dst(ed, E, k);
    float e = als[sn] + ald[dn];
    e = (e >= 0.f) ? e : LEAK * e;
    float v = expf(e);
    ex[k] = v;
    atomicAdd(&ssum[dn], v);
}

__global__ void gat_alpha1(const int* __restrict__ ed, int E, int Etot,
                           const float* __restrict__ ssum, float* __restrict__ ex)
{
    int k = blockIdx.x * blockDim.x + threadIdx.x;
    if (k >= Etot) return;
    int dn = e_dst(ed, E, k);
    ex[k] = ex[k] / fmaxf(ssum[dn], 1e-16f);
}

template<int C>
__global__ void gat_edge_b1(const int* __restrict__ es, const int* __restrict__ ed,
                            int E, int Etot, const unsigned short* __restrict__ h,
                            const float* __restrict__ alpha, float* __restrict__ out)
{
    constexpr int C4 = C / 4;
    int idx = blockIdx.x * blockDim.x + threadIdx.x;
    if (idx >= Etot * C4) return;
    int k = idx / C4, j = (idx - k * C4) * 4;
    int sn = e_src(es, E, k), dn = e_dst(ed, E, k);
    float a = alpha[k];
    ushort4 hv = *reinterpret_cast<const ushort4*>(h + (size_t)sn * C + j);
    float* op = out + (size_t)dn * C + j;
    atomicAdd(op + 0, bf2f(hv.x) * a);
    atomicAdd(op + 1, bf2f(hv.y) * a);
    atomicAdd(op + 2, bf2f(hv.z) * a);
    atomicAdd(op + 3, bf2f(hv.w) * a);
}

// ---- GCN -------------------------------------------------------------------
__global__ void gcn_deg(const int* __restrict__ ed, int E, int Etot, float* __restrict__ deg)
{
    int k = blockIdx.x * blockDim.x + threadIdx.x;
    if (k >= Etot) return;
    atomicAdd(&deg[e_dst(ed, E, k)], 1.f);
}
__global__ void deg_fin(float* __restrict__ deg, int n)
{
    int i = blockIdx.x * blockDim.x + threadIdx.x;
    if (i < n) deg[i] = rsqrtf(fmaxf(deg[i], 1.f));
}
template<int C>
__global__ void gcn_agg1(const int* __restrict__ es, const int* __restrict__ ed,
                         int E, int Etot, const unsigned short* __restrict__ h,
                         const float* __restrict__ dinv, float* __restrict__ out)
{
    constexpr int C4 = C / 4;
    int idx = blockIdx.x * blockDim.x + threadIdx.x;
    if (idx >= Etot * C4) return;
    int k = idx / C4, j = (idx - k * C4) * 4;
    int sn = e_src(es, E, k), dn = e_dst(ed, E, k);
    float nrm = dinv[sn] * dinv[dn];
    ushort4 hv = *reinterpret_cast<const ushort4*>(h + (size_t)sn * C + j);
    float* op = out + (size_t)dn * C + j;
    atomicAdd(op + 0, bf2f(hv.x) * nrm);
    atomicAdd(op + 1, bf2f(hv.y) * nrm);
    atomicAdd(op + 2, bf2f(hv.z) * nrm);
    atomicAdd(op + 3, bf2f(hv.w) * nrm);
}

// ---- BatchNorm -------------------------------------------------------------
__global__ void bn_stats(const float* __restrict__ x, float* __restrict__ sums,
                         float* __restrict__ sqs, int M, int D, int rows_per)
{
    int col = blockIdx.x * blockDim.x + threadIdx.x;
    if (col >= D) return;
    int r0 = blockIdx.y * rows_per;
    int r1 = min(r0 + rows_per, M);
    float s = 0.f, q = 0.f;
    for (int r = r0; r < r1; ++r) {
        float v = x[(size_t)r * D + col];
        s += v; q += v * v;
    }
    atomicAdd(&sums[col], s);
    atomicAdd(&sqs[col], q);
}

__global__ void bn_fin(const float* __restrict__ sums, const float* __restrict__ sqs,
                       const float* __restrict__ g, const float* __restrict__ b,
                       float* __restrict__ scale, float* __restrict__ shift,
                       int D, float invM)
{
    int c = blockIdx.x * blockDim.x + threadIdx.x;
    if (c >= D) return;
    float mu = sums[c] * invM;
    float var = sqs[c] * invM - mu * mu;
    float rs = rsqrtf(var + BN_EPS) * g[c];
    scale[c] = rs;
    shift[c] = b[c] - mu * rs;
}

// relu(bn(x)) fp32 in place (compact layout, stride D)
__global__ void bn_apply_relu(float* __restrict__ x, const float* __restrict__ scale,
                              const float* __restrict__ shift, int total, int D)
{
    int i = blockIdx.x * blockDim.x + threadIdx.x;
    if (i >= total) return;
    int c = i % D;
    x[i] = fmaxf(x[i] * scale[c] + shift[c], 0.f);
}

// relu(bn(x)) fp32 -> bf16 dst with row stride ldd (dst pre-offset to column block)
__global__ void bn_apply_bf16(const float* __restrict__ x, const float* __restrict__ scale,
                              const float* __restrict__ shift, unsigned short* __restrict__ dst,
                              int total, int Cb, int ldd)
{
    int i = blockIdx.x * blockDim.x + threadIdx.x;
    if (i >= total) return;
    int r = i / Cb, c = i - r * Cb;
    float v = fmaxf(x[i] * scale[c] + shift[c], 0.f);
    dst[(size_t)r * ldd + c] = f2bf(v);
}

__global__ void conv_f2b(const float* __restrict__ src, unsigned short* __restrict__ dst, int n)
{
    int i = blockIdx.x * blockDim.x + threadIdx.x;
    if (i < n) dst[i] = f2bf(src[i]);
}

// ---- Pooling ---------------------------------------------------------------
__global__ void pool_cnt(const int* __restrict__ batch, float* __restrict__ cnt, int n)
{
    int i = blockIdx.x * blockDim.x + threadIdx.x;
    if (i < n) atomicAdd(&cnt[batch[i]], 1.f);
}
__global__ void pool_scatter(const float* __restrict__ h, const int* __restrict__ batch,
                             float* __restrict__ zgap, int* __restrict__ gmp, int n)
{
    int idx = blockIdx.x * blockDim.x + threadIdx.x;
    if (idx >= n * 256) return;
    int i = idx >> 8, c = idx & 255;
    int g = batch[i];
    float v = h[(size_t)i * 256 + c];
    atomicAdd(&zgap[(size_t)g * 640 + c], v);
    atomicMax(&gmp[g * 256 + c], __float_as_int(v));   // v >= 0 post-relu
}
__global__ void pool_fin(float* __restrict__ z, const int* __restrict__ gmp,
                         const float* __restrict__ cnt, int G_)
{
    int idx = blockIdx.x * blockDim.x + threadIdx.x;
    if (idx >= G_ * 256) return;
    int g = idx >> 8, c = idx & 255;
    z[(size_t)g * 640 + c] = z[(size_t)g * 640 + c] / fmaxf(cnt[g], 1.f);
    float m = __int_as_float(gmp[g * 256 + c]);
    z[(size_t)g * 640 + 256 + c] = fmaxf(m, 0.f);      // -inf (empty group) -> 0
}
__global__ void fill_i32(int* __restrict__ p, int v, int n)
{
    int i = blockIdx.x * blockDim.x + threadIdx.x;
    if (i < n) p[i] = v;
}

__global__ void final_head(const float* __restrict__ f1, const float* __restrict__ Wf2,
                           const float* __restrict__ bf2, float* __restrict__ out, int G_, int D)
{
    int w = (int)(((long long)blockIdx.x * blockDim.x + threadIdx.x) >> 6);
    int lane = threadIdx.x & 63;
    if (w >= G_) return;
    float s = 0.f;
    for (int c = lane; c < D; c += 64) s += f1[(size_t)w * D + c] * Wf2[c];
    #pragma unroll
    for (int off = 32; off; off >>= 1) s += __shfl_down(s, off);
    if (lane == 0) out[w] = 1.f / (1.f + expf(-(s + bf2[0])));
}

__global__ void sentinel(float* __restrict__ out, int n, float v)
{
    int i = blockIdx.x * blockDim.x + threadIdx.x;
    if (i < n) out[i] = v;
}

// ---------------------------------------------------------------------------
extern "C" void kernel_launch(void* const* d_in, const int* in_sizes, int n_in,
                              void* d_out, int out_size, void* d_ws, size_t ws_size,
                              hipStream_t stream)
{
    const float* x    = (const float*)d_in[0];
    const int*   ei   = (const int*)d_in[1];
    const int*   batch= (const int*)d_in[2];
    const float* sfp  = (const float*)d_in[3];
    const float* W1   = (const float*)d_in[4];
    const float* a1s  = (const float*)d_in[5];
    const float* a1d  = (const float*)d_in[6];
    const float* bn1g = (const float*)d_in[8];
    const float* bn1b = (const float*)d_in[9];
    const float* W2   = (const float*)d_in[10];
    const float* a2s  = (const float*)d_in[11];
    const float* a2d  = (const float*)d_in[12];
    const float* bn2g = (const float*)d_in[14];
    const float* bn2b = (const float*)d_in[15];
    const float* Wg   = (const float*)d_in[16];
    const float* bn3g = (const float*)d_in[18];
    const float* bn3b = (const float*)d_in[19];
    const float* Wsm  = (const float*)d_in[20];
    const float* bsm  = (const float*)d_in[21];
    const float* Wf1  = (const float*)d_in[22];
    const float* bnfg = (const float*)d_in[24];
    const float* bnfb = (const float*)d_in[25];
    const float* Wf2  = (const float*)d_in[26];
    const float* bf2  = (const float*)d_in[27];
    float* outp = (float*)d_out;

    const int N    = in_sizes[0] / 64;
    const int E    = in_sizes[1] / 2;
    const int G_   = in_sizes[3] / 128;
    const int Etot = E + N;
    const int* esrc = ei;
    const int* edst = ei + E;

    // ---- workspace (element offsets in fp32 units); peak ~185 MB ----
    float* ws = (float*)d_ws;
    size_t off = 0;
    float* accA  = ws + off; off += (size_t)N * 256;          // fp32 accum (also o3)
    float* h3acc = ws + off; off += (size_t)N * 256;          // GCN GEMM accumulator
    unsigned short* o1n = (unsigned short*)(ws + off); off += (size_t)N * 256; // N*512 bf16
    unsigned short* hb  = (unsigned short*)(ws + off); off += (size_t)N * 128; // N*256 bf16
    float* als = ws + off; off += N;
    float* ald = ws + off; off += N;
    float* ex  = ws + off; off += Etot;
    float* ssum= ws + off; off += N;
    float* deg = ws + off; off += N;
    float* bsum= ws + off; off += 1024;
    float* bsq = ws + off; off += 1024;
    float* bsc = ws + off; off += 1024;
    float* bsh = ws + off; off += 1024;
    float* cnt = ws + off; off += G_;
    float* z   = ws + off; off += (size_t)G_ * 640;
    int*  gmp  = (int*)(ws + off); off += (size_t)G_ * 256;
    float* f1  = ws + off; off += (size_t)G_ * 128;
    size_t need = off * 4;
    if (ws_size < need) {   // diagnostic: absmax will read ~ws_size in MiB
        sentinel<<<cdiv(out_size, 256), 256, 0, stream>>>(outp, out_size, (float)(ws_size >> 20));
        return;
    }

    const int BLK = 256;
    dim3 blk(BLK);

    // ================= GAT layer 1 (64 -> 4 heads x 128), head-blocked =====
    for (int hh = 0; hh < 4; ++hh) {
        { dim3 g(2, cdiv(N, 64));
          gemm_t<float, unsigned short, false, false><<<g, blk, 0, stream>>>(
              x, W1 + hh * 128, nullptr, hb, N, 64, 128, 64, 512, 128); }
        attn_logits1<<<cdiv((long long)N * 64, BLK), blk, 0, stream>>>(
            hb, a1s + hh * 128, a1d + hh * 128, als, ald, N, 128);
        hipMemsetAsync(ssum, 0, (size_t)N * 4, stream);
        hipMemsetAsync(accA, 0, (size_t)N * 128 * 4, stream);
        gat_edge_a1<<<cdiv(Etot, BLK), blk, 0, stream>>>(esrc, edst, E, Etot, als, ald, ex, ssum);
        gat_alpha1<<<cdiv(Etot, BLK), blk, 0, stream>>>(edst, E, Etot, ssum, ex);
        gat_edge_b1<128><<<cdiv((long long)Etot * 32, BLK), blk, 0, stream>>>(
            esrc, edst, E, Etot, hb, ex, accA);
        hipMemsetAsync(bsum, 0, 2048 * 4, stream);
        { dim3 g(1, 128); bn_stats<<<g, blk, 0, stream>>>(accA, bsum, bsq, N, 128, cdiv(N, 128)); }
        bn_fin<<<1, blk, 0, stream>>>(bsum, bsq, bn1g + hh * 128, bn1b + hh * 128, bsc, bsh, 128, 1.f / N);
        bn_apply_bf16<<<cdiv((long long)N * 128, BLK), blk, 0, stream>>>(
            accA, bsc, bsh, o1n + hh * 128, N * 128, 128, 512);
    }

    // ================= GAT layer 2 (512 -> 4 heads x 256) + fused GCN GEMM =
    hipMemsetAsync(h3acc, 0, (size_t)N * 256 * 4, stream);
    for (int hh = 0; hh < 4; ++hh) {
        { dim3 g(4, cdiv(N, 64));
          gemm_t<unsigned short, unsigned short, false, false><<<g, blk, 0, stream>>>(
              o1n, W2 + hh * 256, nullptr, hb, N, 512, 256, 512, 1024, 256); }
        attn_logits1<<<cdiv((long long)N * 64, BLK), blk, 0, stream>>>(
            hb, a2s + hh * 256, a2d + hh * 256, als, ald, N, 256);
        hipMemsetAsync(ssum, 0, (size_t)N * 4, stream);
        hipMemsetAsync(accA, 0, (size_t)N * 256 * 4, stream);
        gat_edge_a1<<<cdiv(Etot, BLK), blk, 0, stream>>>(esrc, edst, E, Etot, als, ald, ex, ssum);
        gat_alpha1<<<cdiv(Etot, BLK), blk, 0, stream>>>(edst, E, Etot, ssum, ex);
        gat_edge_b1<256><<<cdiv((long long)Etot * 64, BLK), blk, 0, stream>>>(
            esrc, edst, E, Etot, hb, ex, accA);
        hipMemsetAsync(bsum, 0, 2048 * 4, stream);
        { dim3 g(1, 128); bn_stats<<<g, blk, 0, stream>>>(accA, bsum, bsq, N, 256, cdiv(N, 128)); }
        bn_fin<<<1, blk, 0, stream>>>(bsum, bsq, bn2g + hh * 256, bn2b + hh * 256, bsc, bsh, 256, 1.f / N);
        bn_apply_bf16<<<cdiv((long long)N * 256, BLK), blk, 0, stream>>>(
            accA, bsc, bsh, hb, N * 256, 256, 256);
        // h3acc += bn2(head block) @ Wg[hh*256 : (hh+1)*256, :]
        { dim3 g(4, cdiv(N, 64));
          gemm_t<unsigned short, float, true, false><<<g, blk, 0, stream>>>(
              hb, Wg + (size_t)hh * 256 * 256, nullptr, h3acc, N, 256, 256, 256, 256, 256); }
    }

    // ================= GCN aggregation + BN3 ================================
    conv_f2b<<<cdiv((long long)N * 256, BLK), blk, 0, stream>>>(h3acc, hb, N * 256);
    hipMemsetAsync(deg, 0, (size_t)N * 4, stream);
    hipMemsetAsync(accA, 0, (size_t)N * 256 * 4, stream);
    gcn_deg<<<cdiv(Etot, BLK), blk, 0, stream>>>(edst, E, Etot, deg);
    deg_fin<<<cdiv(N, BLK), blk, 0, stream>>>(deg, N);
    gcn_agg1<256><<<cdiv((long long)Etot * 64, BLK), blk, 0, stream>>>(
        esrc, edst, E, Etot, hb, deg, accA);
    hipMemsetAsync(bsum, 0, 2048 * 4, stream);
    { dim3 g(1, 128); bn_stats<<<g, blk, 0, stream>>>(accA, bsum, bsq, N, 256, cdiv(N, 128)); }
    bn_fin<<<1, blk, 0, stream>>>(bsum, bsq, bn3g, bn3b, bsc, bsh, 256, 1.f / N);
    bn_apply_relu<<<cdiv((long long)N * 256, BLK), blk, 0, stream>>>(accA, bsc, bsh, N * 256, 256);

    // ================= Pooling ==============================================
    hipMemsetAsync(z, 0, (size_t)G_ * 640 * 4, stream);
    hipMemsetAsync(cnt, 0, (size_t)G_ * 4, stream);
    fill_i32<<<cdiv(G_ * 256, BLK), blk, 0, stream>>>(gmp, 0xFF800000, G_ * 256);
    pool_cnt<<<cdiv(N, BLK), blk, 0, stream>>>(batch, cnt, N);
    pool_scatter<<<cdiv((long long)N * 256, BLK), blk, 0, stream>>>(accA, batch, z, gmp, N);
    pool_fin<<<cdiv(G_ * 256, BLK), blk, 0, stream>>>(z, gmp, cnt, G_);

    // solvent MLP -> z[:, 512:640]
    { dim3 g(2, cdiv(G_, 64));
      gemm_t<float, float, false, true><<<g, blk, 0, stream>>>(
          sfp, Wsm, bsm, z + 512, G_, 128, 128, 128, 128, 640); }

    // ================= Head =================================================
    { dim3 g(2, cdiv(G_, 64));
      gemm_t<float, float, false, false><<<g, blk, 0, stream>>>(
          z, Wf1, nullptr, f1, G_, 640, 128, 640, 128, 128); }
    hipMemsetAsync(bsum, 0, 2048 * 4, stream);
    { dim3 g(1, 8); bn_stats<<<g, blk, 0, stream>>>(f1, bsum, bsq, G_, 128, cdiv(G_, 8)); }
    bn_fin<<<1, blk, 0, stream>>>(bsum, bsq, bnfg, bnfb, bsc, bsh, 128, 1.f / G_);
    bn_apply_relu<<<cdiv((long long)G_ * 128, BLK), blk, 0, stream>>>(f1, bsc, bsh, G_ * 128, 128);
    final_head<<<cdiv((long long)G_ * 64, BLK), blk, 0, stream>>>(f1, Wf2, bf2, outp, G_, 128);
}

// Round 3
// 3824.354 us; speedup vs baseline: 2.4649x; 2.4649x over previous
//
#include <hip/hip_runtime.h>
#include <cmath>

#define LEAK 0.2f
#define BN_EPS 1e-5f

static inline int cdiv(long long a, long long b){ return (int)((a + b - 1) / b); }

// ---- bf16 helpers (manual, RNE) -------------------------------------------
__device__ __forceinline__ float bf2f(unsigned short u){
    return __uint_as_float(((unsigned int)u) << 16);
}
__device__ __forceinline__ unsigned short f2bf(float f){
    unsigned int u = __float_as_uint(f);
    u += 0x7FFFu + ((u >> 16) & 1u);
    return (unsigned short)(u >> 16);
}
__device__ __forceinline__ float ldA(const float* p){ return *p; }
__device__ __forceinline__ float ldA(const unsigned short* p){ return bf2f(*p); }
__device__ __forceinline__ void stC(float* p, float v){ *p = v; }
__device__ __forceinline__ void stC(unsigned short* p, float v){ *p = f2bf(v); }

// ---------------------------------------------------------------------------
// Tiled GEMM: C[M,Nc] (+)= A[M,K] @ B[K,Nc] (+bias, optional relu)
// ---------------------------------------------------------------------------
template<typename TA, typename TC, bool ACC, bool RELU>
__global__ __launch_bounds__(256) void gemm_t(
    const TA* __restrict__ A, const float* __restrict__ B,
    const float* __restrict__ bias, TC* __restrict__ C,
    int M, int K, int Nc, int lda, int ldb, int ldc)
{
    __shared__ float As[16][65];
    __shared__ float Bs[16][64];
    const int tid = threadIdx.x;
    const int tx = tid & 15, ty = tid >> 4;
    const int row0 = blockIdx.y * 64, col0 = blockIdx.x * 64;
    float acc[4][4] = {};

    for (int k0 = 0; k0 < K; k0 += 16) {
        #pragma unroll
        for (int i = 0; i < 4; ++i) {
            int f = tid * 4 + i, r = f >> 4, c = f & 15;
            int gr = row0 + r;
            As[c][r] = (gr < M) ? ldA(&A[(size_t)gr * lda + k0 + c]) : 0.f;
        }
        #pragma unroll
        for (int i = 0; i < 4; ++i) {
            int f = tid * 4 + i, r = f >> 6, c = f & 63;
            int gc = col0 + c;
            Bs[r][c] = (gc < Nc) ? B[(size_t)(k0 + r) * ldb + gc] : 0.f;
        }
        __syncthreads();
        #pragma unroll
        for (int kk = 0; kk < 16; ++kk) {
            float a[4], b[4];
            #pragma unroll
            for (int i = 0; i < 4; ++i) a[i] = As[kk][ty + 16 * i];
            #pragma unroll
            for (int j = 0; j < 4; ++j) b[j] = Bs[kk][tx + 16 * j];
            #pragma unroll
            for (int i = 0; i < 4; ++i)
                #pragma unroll
                for (int j = 0; j < 4; ++j)
                    acc[i][j] += a[i] * b[j];
        }
        __syncthreads();
    }
    #pragma unroll
    for (int i = 0; i < 4; ++i) {
        int r = row0 + ty + 16 * i;
        if (r >= M) continue;
        #pragma unroll
        for (int j = 0; j < 4; ++j) {
            int c = col0 + tx + 16 * j;
            if (c >= Nc) continue;
            float v = acc[i][j];
            if (bias) v += bias[c];
            if constexpr (ACC) v += reinterpret_cast<const float*>(C)[(size_t)r * ldc + c];
            if constexpr (RELU) v = fmaxf(v, 0.f);
            stC(&C[(size_t)r * ldc + c], v);
        }
    }
}

// ---- attention logits, single head: wave per node --------------------------
__global__ void attn_logits1(const unsigned short* __restrict__ h,
                             const float* __restrict__ avs, const float* __restrict__ avd,
                             float* __restrict__ als, float* __restrict__ ald, int N, int C)
{
    int w = (int)(((long long)blockIdx.x * blockDim.x + threadIdx.x) >> 6);
    int lane = threadIdx.x & 63;
    if (w >= N) return;
    const unsigned short* hp = h + (size_t)w * C;
    float s = 0.f, d = 0.f;
    for (int c = lane; c < C; c += 64) {
        float v = bf2f(hp[c]);
        s += v * avs[c];
        d += v * avd[c];
    }
    #pragma unroll
    for (int off = 32; off; off >>= 1) {
        s += __shfl_down(s, off);
        d += __shfl_down(d, off);
    }
    if (lane == 0) { als[w] = s; ald[w] = d; }
}

// ============================ CSR build ====================================
__device__ __forceinline__ int e_src(const int* es, int E, int k){ return k < E ? es[k] : k - E; }
__device__ __forceinline__ int e_dst(const int* ed, int E, int k){ return k < E ? ed[k] : k - E; }

__global__ void fill_i32(int* __restrict__ p, int v, int n)
{
    int i = blockIdx.x * blockDim.x + threadIdx.x;
    if (i < n) p[i] = v;
}

__global__ void hist_dst(const int* __restrict__ ed, int E, int* __restrict__ cnt)
{
    int k = blockIdx.x * blockDim.x + threadIdx.x;
    if (k < E) atomicAdd(&cnt[ed[k]], 1);
}

// single-block exclusive scan (1024 threads, chunked Hillis-Steele)
__global__ __launch_bounds__(1024) void scan_excl(const int* __restrict__ cnt,
                                                  int* __restrict__ rowptr, int n)
{
    __shared__ int buf[1024];
    __shared__ int carry;
    int t = threadIdx.x;
    if (t == 0) carry = 0;
    __syncthreads();
    for (int base = 0; base < n; base += 1024) {
        int i = base + t;
        int v = (i < n) ? cnt[i] : 0;
        buf[t] = v; __syncthreads();
        #pragma unroll
        for (int off = 1; off < 1024; off <<= 1) {
            int tmp = (t >= off) ? buf[t - off] : 0;
            __syncthreads();
            buf[t] += tmp;
            __syncthreads();
        }
        int incl = buf[t];
        if (i < n) rowptr[i] = carry + incl - v;
        int total = buf[1023];
        __syncthreads();
        if (t == 0) carry += total;
        __syncthreads();
    }
    if (t == 0) rowptr[n] = carry;
}

__global__ void copy_i32(const int* __restrict__ s, int* __restrict__ d, int n)
{
    int i = blockIdx.x * blockDim.x + threadIdx.x;
    if (i < n) d[i] = s[i];
}

__global__ void csr_scatter(const int* __restrict__ es, const int* __restrict__ ed,
                            int E, int Etot, int* __restrict__ cursor, int* __restrict__ col)
{
    int k = blockIdx.x * blockDim.x + threadIdx.x;
    if (k >= Etot) return;
    int sn = e_src(es, E, k), dn = e_dst(ed, E, k);
    int pos = atomicAdd(&cursor[dn], 1);
    col[pos] = sn;
}

__global__ void dinv_from_rowptr(const int* __restrict__ rowptr, float* __restrict__ dinv, int n)
{
    int i = blockIdx.x * blockDim.x + threadIdx.x;
    if (i < n) dinv[i] = rsqrtf(fmaxf((float)(rowptr[i + 1] - rowptr[i]), 1.f));
}

// group lower bounds over sorted batch
__global__ void grp_lb(const int* __restrict__ batch, int N, int G_, int* __restrict__ gptr)
{
    int g = blockIdx.x * blockDim.x + threadIdx.x;
    if (g > G_) return;
    if (g == G_) { gptr[G_] = N; return; }
    int lo = 0, hi = N;
    while (lo < hi) { int mid = (lo + hi) >> 1; if (batch[mid] < g) lo = mid + 1; else hi = mid; }
    gptr[g] = lo;
}

// ============== fused GAT softmax+aggregate (gather, wave per node) ========
template<int C>   // C = 128 (ushort2/lane) or 256 (ushort4/lane)
__global__ void gat_gather(const int* __restrict__ rowptr, const int* __restrict__ col,
                           const unsigned short* __restrict__ h,
                           const float* __restrict__ als, const float* __restrict__ ald,
                           float* __restrict__ out, int N)
{
    constexpr int V = C / 64;
    int w = (int)(((long long)blockIdx.x * blockDim.x + threadIdx.x) >> 6);
    int lane = threadIdx.x & 63;
    if (w >= N) return;
    int r0 = rowptr[w], r1 = rowptr[w + 1];
    float aldn = ald[w];
    float ssum = 0.f;
    for (int e = r0; e < r1; ++e) {
        float t = als[col[e]] + aldn;
        t = (t >= 0.f) ? t : LEAK * t;
        ssum += expf(t);
    }
    float acc[V] = {};
    for (int e = r0; e < r1; ++e) {
        int sn = col[e];
        float t = als[sn] + aldn;
        t = (t >= 0.f) ? t : LEAK * t;
        float a = expf(t);
        const unsigned short* hp = h + (size_t)sn * C + lane * V;
        if constexpr (V == 4) {
            ushort4 hv = *reinterpret_cast<const ushort4*>(hp);
            acc[0] += bf2f(hv.x) * a; acc[1] += bf2f(hv.y) * a;
            acc[2] += bf2f(hv.z) * a; acc[3] += bf2f(hv.w) * a;
        } else {
            ushort2 hv = *reinterpret_cast<const ushort2*>(hp);
            acc[0] += bf2f(hv.x) * a; acc[1] += bf2f(hv.y) * a;
        }
    }
    float inv = 1.f / fmaxf(ssum, 1e-16f);
    float* op = out + (size_t)w * C + lane * V;
    #pragma unroll
    for (int i = 0; i < V; ++i) op[i] = acc[i] * inv;
}

// ============== GCN gather (wave per node) =================================
template<int C>
__global__ void gcn_gather(const int* __restrict__ rowptr, const int* __restrict__ col,
                           const unsigned short* __restrict__ h,
                           const float* __restrict__ dinv, float* __restrict__ out, int N)
{
    constexpr int V = C / 64;
    int w = (int)(((long long)blockIdx.x * blockDim.x + threadIdx.x) >> 6);
    int lane = threadIdx.x & 63;
    if (w >= N) return;
    int r0 = rowptr[w], r1 = rowptr[w + 1];
    float acc[V] = {};
    for (int e = r0; e < r1; ++e) {
        int sn = col[e];
        float a = dinv[sn];
        const unsigned short* hp = h + (size_t)sn * C + lane * V;
        if constexpr (V == 4) {
            ushort4 hv = *reinterpret_cast<const ushort4*>(hp);
            acc[0] += bf2f(hv.x) * a; acc[1] += bf2f(hv.y) * a;
            acc[2] += bf2f(hv.z) * a; acc[3] += bf2f(hv.w) * a;
        } else {
            ushort2 hv = *reinterpret_cast<const ushort2*>(hp);
            acc[0] += bf2f(hv.x) * a; acc[1] += bf2f(hv.y) * a;
        }
    }
    float dn = dinv[w];
    float* op = out + (size_t)w * C + lane * V;
    #pragma unroll
    for (int i = 0; i < V; ++i) op[i] = acc[i] * dn;
}

// ---- BatchNorm -------------------------------------------------------------
__global__ void bn_stats(const float* __restrict__ x, float* __restrict__ sums,
                         float* __restrict__ sqs, int M, int D, int rows_per)
{
    int col = blockIdx.x * blockDim.x + threadIdx.x;
    if (col >= D) return;
    int r0 = blockIdx.y * rows_per;
    int r1 = min(r0 + rows_per, M);
    float s = 0.f, q = 0.f;
    for (int r = r0; r < r1; ++r) {
        float v = x[(size_t)r * D + col];
        s += v; q += v * v;
    }
    atomicAdd(&sums[col], s);
    atomicAdd(&sqs[col], q);
}

__global__ void bn_fin(const float* __restrict__ sums, const float* __restrict__ sqs,
                       const float* __restrict__ g, const float* __restrict__ b,
                       float* __restrict__ scale, float* __restrict__ shift,
                       int D, float invM)
{
    int c = blockIdx.x * blockDim.x + threadIdx.x;
    if (c >= D) return;
    float mu = sums[c] * invM;
    float var = sqs[c] * invM - mu * mu;
    float rs = rsqrtf(var + BN_EPS) * g[c];
    scale[c] = rs;
    shift[c] = b[c] - mu * rs;
}

__global__ void bn_apply_relu(float* __restrict__ x, const float* __restrict__ scale,
                              const float* __restrict__ shift, int total, int D)
{
    int i = blockIdx.x * blockDim.x + threadIdx.x;
    if (i >= total) return;
    int c = i % D;
    x[i] = fmaxf(x[i] * scale[c] + shift[c], 0.f);
}

__global__ void bn_apply_bf16(const float* __restrict__ x, const float* __restrict__ scale,
                              const float* __restrict__ shift, unsigned short* __restrict__ dst,
                              int total, int Cb, int ldd)
{
    int i = blockIdx.x * blockDim.x + threadIdx.x;
    if (i >= total) return;
    int r = i / Cb, c = i - r * Cb;
    float v = fmaxf(x[i] * scale[c] + shift[c], 0.f);
    dst[(size_t)r * ldd + c] = f2bf(v);
}

__global__ void conv_f2b(const float* __restrict__ src, unsigned short* __restrict__ dst, int n)
{
    int i = blockIdx.x * blockDim.x + threadIdx.x;
    if (i < n) dst[i] = f2bf(src[i]);
}

// ---- Pooling: block per group, gather over sorted batch -------------------
__global__ __launch_bounds__(256) void pool_gather(const float* __restrict__ h,
                                                   const int* __restrict__ gptr,
                                                   float* __restrict__ z, int G_)
{
    int g = blockIdx.x;
    int c = threadIdx.x;            // 256 channels
    int r0 = gptr[g], r1 = gptr[g + 1];
    float s = 0.f, m = 0.f;         // empty group -> gmp 0 per reference
    for (int i = r0; i < r1; ++i) {
        float v = h[(size_t)i * 256 + c];
        s += v;
        m = fmaxf(m, v);            // values >= 0 post-relu
    }
    float cnt = fmaxf((float)(r1 - r0), 1.f);
    z[(size_t)g * 640 + c] = s / cnt;
    z[(size_t)g * 640 + 256 + c] = m;
}

__global__ void final_head(const float* __restrict__ f1, const float* __restrict__ Wf2,
                           const float* __restrict__ bf2, float* __restrict__ out, int G_, int D)
{
    int w = (int)(((long long)blockIdx.x * blockDim.x + threadIdx.x) >> 6);
    int lane = threadIdx.x & 63;
    if (w >= G_) return;
    float s = 0.f;
    for (int c = lane; c < D; c += 64) s += f1[(size_t)w * D + c] * Wf2[c];
    #pragma unroll
    for (int off = 32; off; off >>= 1) s += __shfl_down(s, off);
    if (lane == 0) out[w] = 1.f / (1.f + expf(-(s + bf2[0])));
}

__global__ void sentinel(float* __restrict__ out, int n, float v)
{
    int i = blockIdx.x * blockDim.x + threadIdx.x;
    if (i < n) out[i] = v;
}

// ---------------------------------------------------------------------------
extern "C" void kernel_launch(void* const* d_in, const int* in_sizes, int n_in,
                              void* d_out, int out_size, void* d_ws, size_t ws_size,
                              hipStream_t stream)
{
    const float* x    = (const float*)d_in[0];
    const int*   ei   = (const int*)d_in[1];
    const int*   batch= (const int*)d_in[2];
    const float* sfp  = (const float*)d_in[3];
    const float* W1   = (const float*)d_in[4];
    const float* a1s  = (const float*)d_in[5];
    const float* a1d  = (const float*)d_in[6];
    const float* bn1g = (const float*)d_in[8];
    const float* bn1b = (const float*)d_in[9];
    const float* W2   = (const float*)d_in[10];
    const float* a2s  = (const float*)d_in[11];
    const float* a2d  = (const float*)d_in[12];
    const float* bn2g = (const float*)d_in[14];
    const float* bn2b = (const float*)d_in[15];
    const float* Wg   = (const float*)d_in[16];
    const float* bn3g = (const float*)d_in[18];
    const float* bn3b = (const float*)d_in[19];
    const float* Wsm  = (const float*)d_in[20];
    const float* bsm  = (const float*)d_in[21];
    const float* Wf1  = (const float*)d_in[22];
    const float* bnfg = (const float*)d_in[24];
    const float* bnfb = (const float*)d_in[25];
    const float* Wf2  = (const float*)d_in[26];
    const float* bf2  = (const float*)d_in[27];
    float* outp = (float*)d_out;

    const int N    = in_sizes[0] / 64;
    const int E    = in_sizes[1] / 2;
    const int G_   = in_sizes[3] / 128;
    const int Etot = E + N;
    const int* esrc = ei;
    const int* edst = ei + E;

    // ---- workspace (fp32-element offsets) ----
    float* ws = (float*)d_ws;
    size_t off = 0;
    float* accA  = ws + off; off += (size_t)N * 256;          // gather output / o3
    float* h3acc = ws + off; off += (size_t)N * 256;          // GCN GEMM accumulator
    unsigned short* o1n = (unsigned short*)(ws + off); off += (size_t)N * 256; // N*512 bf16
    unsigned short* hb  = (unsigned short*)(ws + off); off += (size_t)N * 128; // N*256 bf16
    float* als = ws + off; off += N;
    float* ald = ws + off; off += N;
    float* dinv= ws + off; off += N;
    float* bsum= ws + off; off += 1024;
    float* bsq = ws + off; off += 1024;
    float* bsc = ws + off; off += 1024;
    float* bsh = ws + off; off += 1024;
    float* z   = ws + off; off += (size_t)G_ * 640;
    float* f1  = ws + off; off += (size_t)G_ * 128;
    int* rowptr = (int*)(ws + off); off += (size_t)(N + 1);
    int* colc   = (int*)(ws + off); off += (size_t)Etot;
    int* cursor = (int*)(ws + off); off += (size_t)N;
    int* gptr   = (int*)(ws + off); off += (size_t)(G_ + 1);
    size_t need = off * 4;
    if (ws_size < need) {
        sentinel<<<cdiv(out_size, 256), 256, 0, stream>>>(outp, out_size, (float)(ws_size >> 20));
        return;
    }

    const int BLK = 256;
    dim3 blk(BLK);

    // ================= build CSR (dst -> src) + group bounds ================
    fill_i32<<<cdiv(N, BLK), blk, 0, stream>>>(cursor, 1, N);   // self-loop counts
    hist_dst<<<cdiv(E, BLK), blk, 0, stream>>>(edst, E, cursor);
    scan_excl<<<1, 1024, 0, stream>>>(cursor, rowptr, N);
    copy_i32<<<cdiv(N, BLK), blk, 0, stream>>>(rowptr, cursor, N);
    csr_scatter<<<cdiv(Etot, BLK), blk, 0, stream>>>(esrc, edst, E, Etot, cursor, colc);
    dinv_from_rowptr<<<cdiv(N, BLK), blk, 0, stream>>>(rowptr, dinv, N);
    grp_lb<<<cdiv(G_ + 1, BLK), blk, 0, stream>>>(batch, N, G_, gptr);

    // ================= GAT layer 1 (64 -> 4 heads x 128) ====================
    for (int hh = 0; hh < 4; ++hh) {
        { dim3 g(2, cdiv(N, 64));
          gemm_t<float, unsigned short, false, false><<<g, blk, 0, stream>>>(
              x, W1 + hh * 128, nullptr, hb, N, 64, 128, 64, 512, 128); }
        attn_logits1<<<cdiv((long long)N * 64, BLK), blk, 0, stream>>>(
            hb, a1s + hh * 128, a1d + hh * 128, als, ald, N, 128);
        gat_gather<128><<<cdiv((long long)N * 64, BLK), blk, 0, stream>>>(
            rowptr, colc, hb, als, ald, accA, N);
        hipMemsetAsync(bsum, 0, 2048 * 4, stream);
        { dim3 g(1, 128); bn_stats<<<g, blk, 0, stream>>>(accA, bsum, bsq, N, 128, cdiv(N, 128)); }
        bn_fin<<<1, blk, 0, stream>>>(bsum, bsq, bn1g + hh * 128, bn1b + hh * 128, bsc, bsh, 128, 1.f / N);
        bn_apply_bf16<<<cdiv((long long)N * 128, BLK), blk, 0, stream>>>(
            accA, bsc, bsh, o1n + hh * 128, N * 128, 128, 512);
    }

    // ======= GAT layer 2 (512 -> 4 heads x 256) + fused GCN GEMM ===========
    hipMemsetAsync(h3acc, 0, (size_t)N * 256 * 4, stream);
    for (int hh = 0; hh < 4; ++hh) {
        { dim3 g(4, cdiv(N, 64));
          gemm_t<unsigned short, unsigned short, false, false><<<g, blk, 0, stream>>>(
              o1n, W2 + hh * 256, nullptr, hb, N, 512, 256, 512, 1024, 256); }
        attn_logits1<<<cdiv((long long)N * 64, BLK), blk, 0, stream>>>(
            hb, a2s + hh * 256, a2d + hh * 256, als, ald, N, 256);
        gat_gather<256><<<cdiv((long long)N * 64, BLK), blk, 0, stream>>>(
            rowptr, colc, hb, als, ald, accA, N);
        hipMemsetAsync(bsum, 0, 2048 * 4, stream);
        { dim3 g(1, 128); bn_stats<<<g, blk, 0, stream>>>(accA, bsum, bsq, N, 256, cdiv(N, 128)); }
        bn_fin<<<1, blk, 0, stream>>>(bsum, bsq, bn2g + hh * 256, bn2b + hh * 256, bsc, bsh, 256, 1.f / N);
        bn_apply_bf16<<<cdiv((long long)N * 256, BLK), blk, 0, stream>>>(
            accA, bsc, bsh, hb, N * 256, 256, 256);
        { dim3 g(4, cdiv(N, 64));
          gemm_t<unsigned short, float, true, false><<<g, blk, 0, stream>>>(
              hb, Wg + (size_t)hh * 256 * 256, nullptr, h3acc, N, 256, 256, 256, 256, 256); }
    }

    // ================= GCN aggregation + BN3 ================================
    conv_f2b<<<cdiv((long long)N * 256, BLK), blk, 0, stream>>>(h3acc, hb, N * 256);
    gcn_gather<256><<<cdiv((long long)N * 64, BLK), blk, 0, stream>>>(
        rowptr, colc, hb, dinv, accA, N);
    hipMemsetAsync(bsum, 0, 2048 * 4, stream);
    { dim3 g(1, 128); bn_stats<<<g, blk, 0, stream>>>(accA, bsum, bsq, N, 256, cdiv(N, 128)); }
    bn_fin<<<1, blk, 0, stream>>>(bsum, bsq, bn3g, bn3b, bsc, bsh, 256, 1.f / N);
    bn_apply_relu<<<cdiv((long long)N * 256, BLK), blk, 0, stream>>>(accA, bsc, bsh, N * 256, 256);

    // ================= Pooling (gather over sorted batch) ===================
    pool_gather<<<G_, blk, 0, stream>>>(accA, gptr, z, G_);

    // solvent MLP -> z[:, 512:640]
    { dim3 g(2, cdiv(G_, 64));
      gemm_t<float, float, false, true><<<g, blk, 0, stream>>>(
          sfp, Wsm, bsm, z + 512, G_, 128, 128, 128, 128, 640); }

    // ================= Head =================================================
    { dim3 g(2, cdiv(G_, 64));
      gemm_t<float, float, false, false><<<g, blk, 0, stream>>>(
          z, Wf1, nullptr, f1, G_, 640, 128, 640, 128, 128); }
    hipMemsetAsync(bsum, 0, 2048 * 4, stream);
    { dim3 g(1, 8); bn_stats<<<g, blk, 0, stream>>>(f1, bsum, bsq, G_, 128, cdiv(G_, 8)); }
    bn_fin<<<1, blk, 0, stream>>>(bsum, bsq, bnfg, bnfb, bsc, bsh, 128, 1.f / G_);
    bn_apply_relu<<<cdiv((long long)G_ * 128, BLK), blk, 0, stream>>>(f1, bsc, bsh, G_ * 128, 128);
    final_head<<<cdiv((long long)G_ * 64, BLK), blk, 0, stream>>>(f1, Wf2, bf2, outp, G_, 128);
}

// Round 4
// 2542.702 us; speedup vs baseline: 3.7074x; 1.5041x over previous
//
#include <hip/hip_runtime.h>
#include <cmath>

#define LEAK 0.2f
#define BN_EPS 1e-5f

static inline int cdiv(long long a, long long b){ return (int)((a + b - 1) / b); }

typedef __attribute__((ext_vector_type(8))) short bf16x8;
typedef __attribute__((ext_vector_type(4))) float f32x4;

// ---- bf16 helpers (manual, RNE) -------------------------------------------
__device__ __forceinline__ float bf2f(unsigned short u){
    return __uint_as_float(((unsigned int)u) << 16);
}
__device__ __forceinline__ unsigned short f2bf(float f){
    unsigned int u = __float_as_uint(f);
    u += 0x7FFFu + ((u >> 16) & 1u);
    return (unsigned short)(u >> 16);
}
__device__ __forceinline__ float ldA(const float* p){ return *p; }
__device__ __forceinline__ float ldA(const unsigned short* p){ return bf2f(*p); }
__device__ __forceinline__ void stC(float* p, float v){ *p = v; }
__device__ __forceinline__ void stC(unsigned short* p, float v){ *p = f2bf(v); }

// ---------------------------------------------------------------------------
// MFMA bf16 GEMM: C[M, Nc] (+)= A[M,K] @ B[K,Nc], where Bt = B^T row-major
// [Nc, ldb]. Block tile 128x128 (grid.x = Nc/128), BK = 32, 4 waves per block
// each computing 64x64 as 4x4 grid of 16x16x32 MFMAs. K % 32 == 0.
// LDS rows padded to 40 ushorts -> bank stride 20 -> <=2-way conflicts (free).
// ---------------------------------------------------------------------------
template<typename TC, bool ACC>
__global__ __launch_bounds__(256) void gemm_mfma(
    const unsigned short* __restrict__ A, const unsigned short* __restrict__ Bt,
    TC* __restrict__ C, int M, int K, int lda, int ldb, int ldc)
{
    __shared__ unsigned short As[128 * 40];
    __shared__ unsigned short Bs[128 * 40];
    const int t = threadIdx.x;
    const int row0 = blockIdx.y * 128, col0 = blockIdx.x * 128;
    const int lane = t & 63, wv = t >> 6;
    const int wm = (wv >> 1) << 6, wn = (wv & 1) << 6;
    const int lm = lane & 15, lq = lane >> 4;

    f32x4 acc[4][4] = {};

    for (int k0 = 0; k0 < K; k0 += 32) {
        // stage A tile [128][32]
        #pragma unroll
        for (int q = t; q < 512; q += 256) {
            int r = q >> 2, c8 = (q & 3) << 3;
            int gr = row0 + r; if (gr >= M) gr = M - 1;   // clamp (rows >= M never stored)
            bf16x8 v = *(const bf16x8*)(A + (size_t)gr * lda + k0 + c8);
            *(bf16x8*)&As[r * 40 + c8] = v;
        }
        // stage B^T tile [128][32]
        #pragma unroll
        for (int q = t; q < 512; q += 256) {
            int r = q >> 2, c8 = (q & 3) << 3;
            bf16x8 v = *(const bf16x8*)(Bt + (size_t)(col0 + r) * ldb + k0 + c8);
            *(bf16x8*)&Bs[r * 40 + c8] = v;
        }
        __syncthreads();

        bf16x8 af[4], bf[4];
        #pragma unroll
        for (int mi = 0; mi < 4; ++mi)
            af[mi] = *(const bf16x8*)&As[(wm + mi * 16 + lm) * 40 + lq * 8];
        #pragma unroll
        for (int ni = 0; ni < 4; ++ni)
            bf[ni] = *(const bf16x8*)&Bs[(wn + ni * 16 + lm) * 40 + lq * 8];
        #pragma unroll
        for (int mi = 0; mi < 4; ++mi)
            #pragma unroll
            for (int ni = 0; ni < 4; ++ni)
                acc[mi][ni] = __builtin_amdgcn_mfma_f32_16x16x32_bf16(
                    af[mi], bf[ni], acc[mi][ni], 0, 0, 0);
        __syncthreads();
    }

    // store: D[row = quad*4+reg][col = lane&15]
    #pragma unroll
    for (int mi = 0; mi < 4; ++mi) {
        int row_b = row0 + wm + mi * 16 + lq * 4;
        #pragma unroll
        for (int ni = 0; ni < 4; ++ni) {
            int col = col0 + wn + ni * 16 + lm;
            #pragma unroll
            for (int r = 0; r < 4; ++r) {
                int row = row_b + r;
                if (row < M) {
                    float v = acc[mi][ni][r];
                    if constexpr (ACC) v += reinterpret_cast<const float*>(C)[(size_t)row * ldc + col];
                    stC(&C[(size_t)row * ldc + col], v);
                }
            }
        }
    }
}

// convert fp32 W[K,Nc] -> bf16 W^T[Nc,K]
__global__ void convT(const float* __restrict__ W, unsigned short* __restrict__ Wt, int K, int Nc)
{
    int i = blockIdx.x * blockDim.x + threadIdx.x;
    if (i >= K * Nc) return;
    int k = i / Nc, n = i - k * Nc;
    Wt[(size_t)n * K + k] = f2bf(W[i]);
}

// ---------------------------------------------------------------------------
// fp32 tiled GEMM (small head GEMMs only)
// ---------------------------------------------------------------------------
template<typename TA, typename TC, bool ACC, bool RELU>
__global__ __launch_bounds__(256) void gemm_t(
    const TA* __restrict__ A, const float* __restrict__ B,
    const float* __restrict__ bias, TC* __restrict__ C,
    int M, int K, int Nc, int lda, int ldb, int ldc)
{
    __shared__ float As[16][65];
    __shared__ float Bs[16][64];
    const int tid = threadIdx.x;
    const int tx = tid & 15, ty = tid >> 4;
    const int row0 = blockIdx.y * 64, col0 = blockIdx.x * 64;
    float acc[4][4] = {};

    for (int k0 = 0; k0 < K; k0 += 16) {
        #pragma unroll
        for (int i = 0; i < 4; ++i) {
            int f = tid * 4 + i, r = f >> 4, c = f & 15;
            int gr = row0 + r;
            As[c][r] = (gr < M) ? ldA(&A[(size_t)gr * lda + k0 + c]) : 0.f;
        }
        #pragma unroll
        for (int i = 0; i < 4; ++i) {
            int f = tid * 4 + i, r = f >> 6, c = f & 63;
            int gc = col0 + c;
            Bs[r][c] = (gc < Nc) ? B[(size_t)(k0 + r) * ldb + gc] : 0.f;
        }
        __syncthreads();
        #pragma unroll
        for (int kk = 0; kk < 16; ++kk) {
            float a[4], b[4];
            #pragma unroll
            for (int i = 0; i < 4; ++i) a[i] = As[kk][ty + 16 * i];
            #pragma unroll
            for (int j = 0; j < 4; ++j) b[j] = Bs[kk][tx + 16 * j];
            #pragma unroll
            for (int i = 0; i < 4; ++i)
                #pragma unroll
                for (int j = 0; j < 4; ++j)
                    acc[i][j] += a[i] * b[j];
        }
        __syncthreads();
    }
    #pragma unroll
    for (int i = 0; i < 4; ++i) {
        int r = row0 + ty + 16 * i;
        if (r >= M) continue;
        #pragma unroll
        for (int j = 0; j < 4; ++j) {
            int c = col0 + tx + 16 * j;
            if (c >= Nc) continue;
            float v = acc[i][j];
            if (bias) v += bias[c];
            if constexpr (ACC) v += reinterpret_cast<const float*>(C)[(size_t)r * ldc + c];
            if constexpr (RELU) v = fmaxf(v, 0.f);
            stC(&C[(size_t)r * ldc + c], v);
        }
    }
}

// ---- attention logits, single head: wave per node --------------------------
__global__ void attn_logits1(const unsigned short* __restrict__ h,
                             const float* __restrict__ avs, const float* __restrict__ avd,
                             float* __restrict__ als, float* __restrict__ ald, int N, int C)
{
    int w = (int)(((long long)blockIdx.x * blockDim.x + threadIdx.x) >> 6);
    int lane = threadIdx.x & 63;
    if (w >= N) return;
    const unsigned short* hp = h + (size_t)w * C;
    float s = 0.f, d = 0.f;
    for (int c = lane; c < C; c += 64) {
        float v = bf2f(hp[c]);
        s += v * avs[c];
        d += v * avd[c];
    }
    #pragma unroll
    for (int off = 32; off; off >>= 1) {
        s += __shfl_down(s, off);
        d += __shfl_down(d, off);
    }
    if (lane == 0) { als[w] = s; ald[w] = d; }
}

// ============================ CSR build ====================================
__device__ __forceinline__ int e_src(const int* es, int E, int k){ return k < E ? es[k] : k - E; }
__device__ __forceinline__ int e_dst(const int* ed, int E, int k){ return k < E ? ed[k] : k - E; }

__global__ void fill_i32(int* __restrict__ p, int v, int n)
{
    int i = blockIdx.x * blockDim.x + threadIdx.x;
    if (i < n) p[i] = v;
}

__global__ void hist_dst(const int* __restrict__ ed, int E, int* __restrict__ cnt)
{
    int k = blockIdx.x * blockDim.x + threadIdx.x;
    if (k < E) atomicAdd(&cnt[ed[k]], 1);
}

__global__ __launch_bounds__(1024) void scan_excl(const int* __restrict__ cnt,
                                                  int* __restrict__ rowptr, int n)
{
    __shared__ int buf[1024];
    __shared__ int carry;
    int t = threadIdx.x;
    if (t == 0) carry = 0;
    __syncthreads();
    for (int base = 0; base < n; base += 1024) {
        int i = base + t;
        int v = (i < n) ? cnt[i] : 0;
        buf[t] = v; __syncthreads();
        #pragma unroll
        for (int off = 1; off < 1024; off <<= 1) {
            int tmp = (t >= off) ? buf[t - off] : 0;
            __syncthreads();
            buf[t] += tmp;
            __syncthreads();
        }
        int incl = buf[t];
        if (i < n) rowptr[i] = carry + incl - v;
        int total = buf[1023];
        __syncthreads();
        if (t == 0) carry += total;
        __syncthreads();
    }
    if (t == 0) rowptr[n] = carry;
}

__global__ void copy_i32(const int* __restrict__ s, int* __restrict__ d, int n)
{
    int i = blockIdx.x * blockDim.x + threadIdx.x;
    if (i < n) d[i] = s[i];
}

__global__ void csr_scatter(const int* __restrict__ es, const int* __restrict__ ed,
                            int E, int Etot, int* __restrict__ cursor, int* __restrict__ col)
{
    int k = blockIdx.x * blockDim.x + threadIdx.x;
    if (k >= Etot) return;
    int sn = e_src(es, E, k), dn = e_dst(ed, E, k);
    int pos = atomicAdd(&cursor[dn], 1);
    col[pos] = sn;
}

__global__ void dinv_from_rowptr(const int* __restrict__ rowptr, float* __restrict__ dinv, int n)
{
    int i = blockIdx.x * blockDim.x + threadIdx.x;
    if (i < n) dinv[i] = rsqrtf(fmaxf((float)(rowptr[i + 1] - rowptr[i]), 1.f));
}

__global__ void grp_lb(const int* __restrict__ batch, int N, int G_, int* __restrict__ gptr)
{
    int g = blockIdx.x * blockDim.x + threadIdx.x;
    if (g > G_) return;
    if (g == G_) { gptr[G_] = N; return; }
    int lo = 0, hi = N;
    while (lo < hi) { int mid = (lo + hi) >> 1; if (batch[mid] < g) lo = mid + 1; else hi = mid; }
    gptr[g] = lo;
}

// ============== fused GAT softmax+aggregate (gather, wave per node) ========
template<int C>
__global__ void gat_gather(const int* __restrict__ rowptr, const int* __restrict__ col,
                           const unsigned short* __restrict__ h,
                           const float* __restrict__ als, const float* __restrict__ ald,
                           float* __restrict__ out, int N)
{
    constexpr int V = C / 64;
    int w = (int)(((long long)blockIdx.x * blockDim.x + threadIdx.x) >> 6);
    int lane = threadIdx.x & 63;
    if (w >= N) return;
    int r0 = rowptr[w], r1 = rowptr[w + 1];
    float aldn = ald[w];
    float ssum = 0.f;
    for (int e = r0; e < r1; ++e) {
        float t = als[col[e]] + aldn;
        t = (t >= 0.f) ? t : LEAK * t;
        ssum += expf(t);
    }
    float acc[V] = {};
    for (int e = r0; e < r1; ++e) {
        int sn = col[e];
        float t = als[sn] + aldn;
        t = (t >= 0.f) ? t : LEAK * t;
        float a = expf(t);
        const unsigned short* hp = h + (size_t)sn * C + lane * V;
        if constexpr (V == 4) {
            ushort4 hv = *reinterpret_cast<const ushort4*>(hp);
            acc[0] += bf2f(hv.x) * a; acc[1] += bf2f(hv.y) * a;
            acc[2] += bf2f(hv.z) * a; acc[3] += bf2f(hv.w) * a;
        } else {
            ushort2 hv = *reinterpret_cast<const ushort2*>(hp);
            acc[0] += bf2f(hv.x) * a; acc[1] += bf2f(hv.y) * a;
        }
    }
    float inv = 1.f / fmaxf(ssum, 1e-16f);
    float* op = out + (size_t)w * C + lane * V;
    #pragma unroll
    for (int i = 0; i < V; ++i) op[i] = acc[i] * inv;
}

// ============== GCN gather (wave per node) =================================
template<int C>
__global__ void gcn_gather(const int* __restrict__ rowptr, const int* __restrict__ col,
                           const unsigned short* __restrict__ h,
                           const float* __restrict__ dinv, float* __restrict__ out, int N)
{
    constexpr int V = C / 64;
    int w = (int)(((long long)blockIdx.x * blockDim.x + threadIdx.x) >> 6);
    int lane = threadIdx.x & 63;
    if (w >= N) return;
    int r0 = rowptr[w], r1 = rowptr[w + 1];
    float acc[V] = {};
    for (int e = r0; e < r1; ++e) {
        int sn = col[e];
        float a = dinv[sn];
        const unsigned short* hp = h + (size_t)sn * C + lane * V;
        if constexpr (V == 4) {
            ushort4 hv = *reinterpret_cast<const ushort4*>(hp);
            acc[0] += bf2f(hv.x) * a; acc[1] += bf2f(hv.y) * a;
            acc[2] += bf2f(hv.z) * a; acc[3] += bf2f(hv.w) * a;
        } else {
            ushort2 hv = *reinterpret_cast<const ushort2*>(hp);
            acc[0] += bf2f(hv.x) * a; acc[1] += bf2f(hv.y) * a;
        }
    }
    float dn = dinv[w];
    float* op = out + (size_t)w * C + lane * V;
    #pragma unroll
    for (int i = 0; i < V; ++i) op[i] = acc[i] * dn;
}

// ---- BatchNorm -------------------------------------------------------------
__global__ void bn_stats(const float* __restrict__ x, float* __restrict__ sums,
                         float* __restrict__ sqs, int M, int D, int rows_per)
{
    int col = blockIdx.x * blockDim.x + threadIdx.x;
    if (col >= D) return;
    int r0 = blockIdx.y * rows_per;
    int r1 = min(r0 + rows_per, M);
    float s = 0.f, q = 0.f;
    for (int r = r0; r < r1; ++r) {
        float v = x[(size_t)r * D + col];
        s += v; q += v * v;
    }
    atomicAdd(&sums[col], s);
    atomicAdd(&sqs[col], q);
}

__global__ void bn_fin(const float* __restrict__ sums, const float* __restrict__ sqs,
                       const float* __restrict__ g, const float* __restrict__ b,
                       float* __restrict__ scale, float* __restrict__ shift,
                       int D, float invM)
{
    int c = blockIdx.x * blockDim.x + threadIdx.x;
    if (c >= D) return;
    float mu = sums[c] * invM;
    float var = sqs[c] * invM - mu * mu;
    float rs = rsqrtf(var + BN_EPS) * g[c];
    scale[c] = rs;
    shift[c] = b[c] - mu * rs;
}

__global__ void bn_apply_relu(float* __restrict__ x, const float* __restrict__ scale,
                              const float* __restrict__ shift, int total, int D)
{
    int i = blockIdx.x * blockDim.x + threadIdx.x;
    if (i >= total) return;
    int c = i % D;
    x[i] = fmaxf(x[i] * scale[c] + shift[c], 0.f);
}

__global__ void bn_apply_bf16(const float* __restrict__ x, const float* __restrict__ scale,
                              const float* __restrict__ shift, unsigned short* __restrict__ dst,
                              int total, int Cb, int ldd)
{
    int i = blockIdx.x * blockDim.x + threadIdx.x;
    if (i >= total) return;
    int r = i / Cb, c = i - r * Cb;
    float v = fmaxf(x[i] * scale[c] + shift[c], 0.f);
    dst[(size_t)r * ldd + c] = f2bf(v);
}

__global__ void conv_f2b(const float* __restrict__ src, unsigned short* __restrict__ dst, int n)
{
    int i = blockIdx.x * blockDim.x + threadIdx.x;
    if (i < n) dst[i] = f2bf(src[i]);
}

// ---- Pooling: block per group, gather over sorted batch -------------------
__global__ __launch_bounds__(256) void pool_gather(const float* __restrict__ h,
                                                   const int* __restrict__ gptr,
                                                   float* __restrict__ z, int G_)
{
    int g = blockIdx.x;
    int c = threadIdx.x;
    int r0 = gptr[g], r1 = gptr[g + 1];
    float s = 0.f, m = 0.f;
    for (int i = r0; i < r1; ++i) {
        float v = h[(size_t)i * 256 + c];
        s += v;
        m = fmaxf(m, v);
    }
    float cnt = fmaxf((float)(r1 - r0), 1.f);
    z[(size_t)g * 640 + c] = s / cnt;
    z[(size_t)g * 640 + 256 + c] = m;
}

__global__ void final_head(const float* __restrict__ f1, const float* __restrict__ Wf2,
                           const float* __restrict__ bf2, float* __restrict__ out, int G_, int D)
{
    int w = (int)(((long long)blockIdx.x * blockDim.x + threadIdx.x) >> 6);
    int lane = threadIdx.x & 63;
    if (w >= G_) return;
    float s = 0.f;
    for (int c = lane; c < D; c += 64) s += f1[(size_t)w * D + c] * Wf2[c];
    #pragma unroll
    for (int off = 32; off; off >>= 1) s += __shfl_down(s, off);
    if (lane == 0) out[w] = 1.f / (1.f + expf(-(s + bf2[0])));
}

__global__ void sentinel(float* __restrict__ out, int n, float v)
{
    int i = blockIdx.x * blockDim.x + threadIdx.x;
    if (i < n) out[i] = v;
}

// ---------------------------------------------------------------------------
extern "C" void kernel_launch(void* const* d_in, const int* in_sizes, int n_in,
                              void* d_out, int out_size, void* d_ws, size_t ws_size,
                              hipStream_t stream)
{
    const float* x    = (const float*)d_in[0];
    const int*   ei   = (const int*)d_in[1];
    const int*   batch= (const int*)d_in[2];
    const float* sfp  = (const float*)d_in[3];
    const float* W1   = (const float*)d_in[4];
    const float* a1s  = (const float*)d_in[5];
    const float* a1d  = (const float*)d_in[6];
    const float* bn1g = (const float*)d_in[8];
    const float* bn1b = (const float*)d_in[9];
    const float* W2   = (const float*)d_in[10];
    const float* a2s  = (const float*)d_in[11];
    const float* a2d  = (const float*)d_in[12];
    const float* bn2g = (const float*)d_in[14];
    const float* bn2b = (const float*)d_in[15];
    const float* Wg   = (const float*)d_in[16];
    const float* bn3g = (const float*)d_in[18];
    const float* bn3b = (const float*)d_in[19];
    const float* Wsm  = (const float*)d_in[20];
    const float* bsm  = (const float*)d_in[21];
    const float* Wf1  = (const float*)d_in[22];
    const float* bnfg = (const float*)d_in[24];
    const float* bnfb = (const float*)d_in[25];
    const float* Wf2  = (const float*)d_in[26];
    const float* bf2  = (const float*)d_in[27];
    float* outp = (float*)d_out;

    const int N    = in_sizes[0] / 64;
    const int E    = in_sizes[1] / 2;
    const int G_   = in_sizes[3] / 128;
    const int Etot = E + N;
    const int* esrc = ei;
    const int* edst = ei + E;

    // ---- workspace (fp32-element offsets) ----
    float* ws = (float*)d_ws;
    size_t off = 0;
    float* accA  = ws + off; off += (size_t)N * 256;
    float* h3acc = ws + off; off += (size_t)N * 256;
    unsigned short* o1n = (unsigned short*)(ws + off); off += (size_t)N * 256; // N*512 bf16
    unsigned short* hb  = (unsigned short*)(ws + off); off += (size_t)N * 128; // N*256 bf16
    unsigned short* xb  = (unsigned short*)(ws + off); off += (size_t)N * 32;  // N*64 bf16
    float* als = ws + off; off += N;
    float* ald = ws + off; off += N;
    float* dinv= ws + off; off += N;
    float* bsum= ws + off; off += 1024;
    float* bsq = ws + off; off += 1024;
    float* bsc = ws + off; off += 1024;
    float* bsh = ws + off; off += 1024;
    float* z   = ws + off; off += (size_t)G_ * 640;
    float* f1  = ws + off; off += (size_t)G_ * 128;
    int* rowptr = (int*)(ws + off); off += (size_t)(N + 1);
    int* colc   = (int*)(ws + off); off += (size_t)Etot;
    int* cursor = (int*)(ws + off); off += (size_t)N;
    int* gptr   = (int*)(ws + off); off += (size_t)(G_ + 1);
    unsigned short* W1t = (unsigned short*)(ws + off); off += 64 * 512 / 2;
    unsigned short* W2t = (unsigned short*)(ws + off); off += 512 * 1024 / 2;
    unsigned short* Wgt = (unsigned short*)(ws + off); off += 1024 * 256 / 2;
    size_t need = off * 4;
    if (ws_size < need) {
        sentinel<<<cdiv(out_size, 256), 256, 0, stream>>>(outp, out_size, (float)(ws_size >> 20));
        return;
    }

    const int BLK = 256;
    dim3 blk(BLK);

    // ============ weight prep (bf16 + transpose) + x cast ===================
    convT<<<cdiv(64 * 512, BLK), blk, 0, stream>>>(W1, W1t, 64, 512);
    convT<<<cdiv(512 * 1024, BLK), blk, 0, stream>>>(W2, W2t, 512, 1024);
    convT<<<cdiv(1024 * 256, BLK), blk, 0, stream>>>(Wg, Wgt, 1024, 256);
    conv_f2b<<<cdiv((long long)N * 64, BLK), blk, 0, stream>>>(x, xb, N * 64);

    // ================= build CSR (dst -> src) + group bounds ================
    fill_i32<<<cdiv(N, BLK), blk, 0, stream>>>(cursor, 1, N);   // self-loops
    hist_dst<<<cdiv(E, BLK), blk, 0, stream>>>(edst, E, cursor);
    scan_excl<<<1, 1024, 0, stream>>>(cursor, rowptr, N);
    copy_i32<<<cdiv(N, BLK), blk, 0, stream>>>(rowptr, cursor, N);
    csr_scatter<<<cdiv(Etot, BLK), blk, 0, stream>>>(esrc, edst, E, Etot, cursor, colc);
    dinv_from_rowptr<<<cdiv(N, BLK), blk, 0, stream>>>(rowptr, dinv, N);
    grp_lb<<<cdiv(G_ + 1, BLK), blk, 0, stream>>>(batch, N, G_, gptr);

    // ================= GAT layer 1 (64 -> 4 heads x 128) ====================
    for (int hh = 0; hh < 4; ++hh) {
        { dim3 g(1, cdiv(N, 128));
          gemm_mfma<unsigned short, false><<<g, blk, 0, stream>>>(
              xb, W1t + (size_t)hh * 128 * 64, hb, N, 64, 64, 64, 128); }
        attn_logits1<<<cdiv((long long)N * 64, BLK), blk, 0, stream>>>(
            hb, a1s + hh * 128, a1d + hh * 128, als, ald, N, 128);
        gat_gather<128><<<cdiv((long long)N * 64, BLK), blk, 0, stream>>>(
            rowptr, colc, hb, als, ald, accA, N);
        hipMemsetAsync(bsum, 0, 2048 * 4, stream);
        { dim3 g(1, 128); bn_stats<<<g, blk, 0, stream>>>(accA, bsum, bsq, N, 128, cdiv(N, 128)); }
        bn_fin<<<1, blk, 0, stream>>>(bsum, bsq, bn1g + hh * 128, bn1b + hh * 128, bsc, bsh, 128, 1.f / N);
        bn_apply_bf16<<<cdiv((long long)N * 128, BLK), blk, 0, stream>>>(
            accA, bsc, bsh, o1n + hh * 128, N * 128, 128, 512);
    }

    // ======= GAT layer 2 (512 -> 4 heads x 256) + fused GCN GEMM ===========
    for (int hh = 0; hh < 4; ++hh) {
        { dim3 g(2, cdiv(N, 128));
          gemm_mfma<unsigned short, false><<<g, blk, 0, stream>>>(
              o1n, W2t + (size_t)hh * 256 * 512, hb, N, 512, 512, 512, 256); }
        attn_logits1<<<cdiv((long long)N * 64, BLK), blk, 0, stream>>>(
            hb, a2s + hh * 256, a2d + hh * 256, als, ald, N, 256);
        gat_gather<256><<<cdiv((long long)N * 64, BLK), blk, 0, stream>>>(
            rowptr, colc, hb, als, ald, accA, N);
        hipMemsetAsync(bsum, 0, 2048 * 4, stream);
        { dim3 g(1, 128); bn_stats<<<g, blk, 0, stream>>>(accA, bsum, bsq, N, 256, cdiv(N, 128)); }
        bn_fin<<<1, blk, 0, stream>>>(bsum, bsq, bn2g + hh * 256, bn2b + hh * 256, bsc, bsh, 256, 1.f / N);
        bn_apply_bf16<<<cdiv((long long)N * 256, BLK), blk, 0, stream>>>(
            accA, bsc, bsh, hb, N * 256, 256, 256);
        // h3acc (+)= bn2(head block) @ Wg[hh*256:+256, :]
        { dim3 g(2, cdiv(N, 128));
          if (hh == 0)
              gemm_mfma<float, false><<<g, blk, 0, stream>>>(
                  hb, Wgt + (size_t)hh * 256, h3acc, N, 256, 256, 1024, 256);
          else
              gemm_mfma<float, true><<<g, blk, 0, stream>>>(
                  hb, Wgt + (size_t)hh * 256, h3acc, N, 256, 256, 1024, 256); }
    }

    // ================= GCN aggregation + BN3 ================================
    conv_f2b<<<cdiv((long long)N * 256, BLK), blk, 0, stream>>>(h3acc, hb, N * 256);
    gcn_gather<256><<<cdiv((long long)N * 64, BLK), blk, 0, stream>>>(
        rowptr, colc, hb, dinv, accA, N);
    hipMemsetAsync(bsum, 0, 2048 * 4, stream);
    { dim3 g(1, 128); bn_stats<<<g, blk, 0, stream>>>(accA, bsum, bsq, N, 256, cdiv(N, 128)); }
    bn_fin<<<1, blk, 0, stream>>>(bsum, bsq, bn3g, bn3b, bsc, bsh, 256, 1.f / N);
    bn_apply_relu<<<cdiv((long long)N * 256, BLK), blk, 0, stream>>>(accA, bsc, bsh, N * 256, 256);

    // ================= Pooling ==============================================
    pool_gather<<<G_, blk, 0, stream>>>(accA, gptr, z, G_);

    // solvent MLP -> z[:, 512:640]
    { dim3 g(2, cdiv(G_, 64));
      gemm_t<float, float, false, true><<<g, blk, 0, stream>>>(
          sfp, Wsm, bsm, z + 512, G_, 128, 128, 128, 128, 640); }

    // ================= Head =================================================
    { dim3 g(2, cdiv(G_, 64));
      gemm_t<float, float, false, false><<<g, blk, 0, stream>>>(
          z, Wf1, nullptr, f1, G_, 640, 128, 640, 128, 128); }
    hipMemsetAsync(bsum, 0, 2048 * 4, stream);
    { dim3 g(1, 8); bn_stats<<<g, blk, 0, stream>>>(f1, bsum, bsq, G_, 128, cdiv(G_, 8)); }
    bn_fin<<<1, blk, 0, stream>>>(bsum, bsq, bnfg, bnfb, bsc, bsh, 128, 1.f / G_);
    bn_apply_relu<<<cdiv((long long)G_ * 128, BLK), blk, 0, stream>>>(f1, bsc, bsh, G_ * 128, 128);
    final_head<<<cdiv((long long)G_ * 64, BLK), blk, 0, stream>>>(f1, Wf2, bf2, outp, G_, 128);
}

// Round 5
// 1919.313 us; speedup vs baseline: 4.9116x; 1.3248x over previous
//
#include <hip/hip_runtime.h>
#include <cmath>

#define LEAK 0.2f
#define BN_EPS 1e-5f

static inline int cdiv(long long a, long long b){ return (int)((a + b - 1) / b); }

typedef __attribute__((ext_vector_type(8))) short bf16x8;
typedef __attribute__((ext_vector_type(4))) float f32x4;

// ---- bf16 helpers (manual, RNE) -------------------------------------------
__device__ __forceinline__ float bf2f(unsigned short u){
    return __uint_as_float(((unsigned int)u) << 16);
}
__device__ __forceinline__ unsigned short f2bf(float f){
    unsigned int u = __float_as_uint(f);
    u += 0x7FFFu + ((u >> 16) & 1u);
    return (unsigned short)(u >> 16);
}
__device__ __forceinline__ float ldA(const float* p){ return *p; }
__device__ __forceinline__ float ldA(const unsigned short* p){ return bf2f(*p); }
__device__ __forceinline__ void stC(float* p, float v){ *p = v; }
__device__ __forceinline__ void stC(unsigned short* p, float v){ *p = f2bf(v); }

// ---------------------------------------------------------------------------
// MFMA bf16 GEMM (128x128 tile, BK=32, 4 waves x 4x4 16x16x32 MFMAs)
// ---------------------------------------------------------------------------
template<typename TC, bool ACC>
__global__ __launch_bounds__(256) void gemm_mfma(
    const unsigned short* __restrict__ A, const unsigned short* __restrict__ Bt,
    TC* __restrict__ C, int M, int K, int lda, int ldb, int ldc)
{
    __shared__ unsigned short As[128 * 40];
    __shared__ unsigned short Bs[128 * 40];
    const int t = threadIdx.x;
    const int row0 = blockIdx.y * 128, col0 = blockIdx.x * 128;
    const int lane = t & 63, wv = t >> 6;
    const int wm = (wv >> 1) << 6, wn = (wv & 1) << 6;
    const int lm = lane & 15, lq = lane >> 4;

    f32x4 acc[4][4] = {};

    for (int k0 = 0; k0 < K; k0 += 32) {
        #pragma unroll
        for (int q = t; q < 512; q += 256) {
            int r = q >> 2, c8 = (q & 3) << 3;
            int gr = row0 + r; if (gr >= M) gr = M - 1;
            bf16x8 v = *(const bf16x8*)(A + (size_t)gr * lda + k0 + c8);
            *(bf16x8*)&As[r * 40 + c8] = v;
        }
        #pragma unroll
        for (int q = t; q < 512; q += 256) {
            int r = q >> 2, c8 = (q & 3) << 3;
            bf16x8 v = *(const bf16x8*)(Bt + (size_t)(col0 + r) * ldb + k0 + c8);
            *(bf16x8*)&Bs[r * 40 + c8] = v;
        }
        __syncthreads();

        bf16x8 af[4], bfr[4];
        #pragma unroll
        for (int mi = 0; mi < 4; ++mi)
            af[mi] = *(const bf16x8*)&As[(wm + mi * 16 + lm) * 40 + lq * 8];
        #pragma unroll
        for (int ni = 0; ni < 4; ++ni)
            bfr[ni] = *(const bf16x8*)&Bs[(wn + ni * 16 + lm) * 40 + lq * 8];
        #pragma unroll
        for (int mi = 0; mi < 4; ++mi)
            #pragma unroll
            for (int ni = 0; ni < 4; ++ni)
                acc[mi][ni] = __builtin_amdgcn_mfma_f32_16x16x32_bf16(
                    af[mi], bfr[ni], acc[mi][ni], 0, 0, 0);
        __syncthreads();
    }

    #pragma unroll
    for (int mi = 0; mi < 4; ++mi) {
        int row_b = row0 + wm + mi * 16 + lq * 4;
        #pragma unroll
        for (int ni = 0; ni < 4; ++ni) {
            int col = col0 + wn + ni * 16 + lm;
            #pragma unroll
            for (int r = 0; r < 4; ++r) {
                int row = row_b + r;
                if (row < M) {
                    float v = acc[mi][ni][r];
                    if constexpr (ACC) v += reinterpret_cast<const float*>(C)[(size_t)row * ldc + col];
                    stC(&C[(size_t)row * ldc + col], v);
                }
            }
        }
    }
}

// convert fp32 W[K,Nc] -> bf16 W^T[Nc,K]
__global__ void convT(const float* __restrict__ W, unsigned short* __restrict__ Wt, int K, int Nc)
{
    int i = blockIdx.x * blockDim.x + threadIdx.x;
    if (i >= K * Nc) return;
    int k = i / Nc, n = i - k * Nc;
    Wt[(size_t)n * K + k] = f2bf(W[i]);
}

// ---------------------------------------------------------------------------
// fp32 tiled GEMM (small head GEMMs only)
// ---------------------------------------------------------------------------
template<typename TA, typename TC, bool ACC, bool RELU>
__global__ __launch_bounds__(256) void gemm_t(
    const TA* __restrict__ A, const float* __restrict__ B,
    const float* __restrict__ bias, TC* __restrict__ C,
    int M, int K, int Nc, int lda, int ldb, int ldc)
{
    __shared__ float As[16][65];
    __shared__ float Bs[16][64];
    const int tid = threadIdx.x;
    const int tx = tid & 15, ty = tid >> 4;
    const int row0 = blockIdx.y * 64, col0 = blockIdx.x * 64;
    float acc[4][4] = {};

    for (int k0 = 0; k0 < K; k0 += 16) {
        #pragma unroll
        for (int i = 0; i < 4; ++i) {
            int f = tid * 4 + i, r = f >> 4, c = f & 15;
            int gr = row0 + r;
            As[c][r] = (gr < M) ? ldA(&A[(size_t)gr * lda + k0 + c]) : 0.f;
        }
        #pragma unroll
        for (int i = 0; i < 4; ++i) {
            int f = tid * 4 + i, r = f >> 6, c = f & 63;
            int gc = col0 + c;
            Bs[r][c] = (gc < Nc) ? B[(size_t)(k0 + r) * ldb + gc] : 0.f;
        }
        __syncthreads();
        #pragma unroll
        for (int kk = 0; kk < 16; ++kk) {
            float a[4], b[4];
            #pragma unroll
            for (int i = 0; i < 4; ++i) a[i] = As[kk][ty + 16 * i];
            #pragma unroll
            for (int j = 0; j < 4; ++j) b[j] = Bs[kk][tx + 16 * j];
            #pragma unroll
            for (int i = 0; i < 4; ++i)
                #pragma unroll
                for (int j = 0; j < 4; ++j)
                    acc[i][j] += a[i] * b[j];
        }
        __syncthreads();
    }
    #pragma unroll
    for (int i = 0; i < 4; ++i) {
        int r = row0 + ty + 16 * i;
        if (r >= M) continue;
        #pragma unroll
        for (int j = 0; j < 4; ++j) {
            int c = col0 + tx + 16 * j;
            if (c >= Nc) continue;
            float v = acc[i][j];
            if (bias) v += bias[c];
            if constexpr (ACC) v += reinterpret_cast<const float*>(C)[(size_t)r * ldc + c];
            if constexpr (RELU) v = fmaxf(v, 0.f);
            stC(&C[(size_t)r * ldc + c], v);
        }
    }
}

// ---- attention logits ------------------------------------------------------
__global__ void attn_logits1(const unsigned short* __restrict__ h,
                             const float* __restrict__ avs, const float* __restrict__ avd,
                             float* __restrict__ als, float* __restrict__ ald, int N, int C)
{
    int w = (int)(((long long)blockIdx.x * blockDim.x + threadIdx.x) >> 6);
    int lane = threadIdx.x & 63;
    if (w >= N) return;
    const unsigned short* hp = h + (size_t)w * C;
    float s = 0.f, d = 0.f;
    for (int c = lane; c < C; c += 64) {
        float v = bf2f(hp[c]);
        s += v * avs[c];
        d += v * avd[c];
    }
    #pragma unroll
    for (int off = 32; off; off >>= 1) {
        s += __shfl_down(s, off);
        d += __shfl_down(d, off);
    }
    if (lane == 0) { als[w] = s; ald[w] = d; }
}

// ============================ CSR build ====================================
__device__ __forceinline__ int e_src(const int* es, int E, int k){ return k < E ? es[k] : k - E; }
__device__ __forceinline__ int e_dst(const int* ed, int E, int k){ return k < E ? ed[k] : k - E; }

__global__ void fill_i32(int* __restrict__ p, int v, int n)
{
    int i = blockIdx.x * blockDim.x + threadIdx.x;
    if (i < n) p[i] = v;
}

__global__ void hist_dst(const int* __restrict__ ed, int E, int* __restrict__ cnt)
{
    int k = blockIdx.x * blockDim.x + threadIdx.x;
    if (k < E) atomicAdd(&cnt[ed[k]], 1);
}

__global__ __launch_bounds__(1024) void scan_excl(const int* __restrict__ cnt,
                                                  int* __restrict__ rowptr, int n)
{
    __shared__ int buf[1024];
    __shared__ int carry;
    int t = threadIdx.x;
    if (t == 0) carry = 0;
    __syncthreads();
    for (int base = 0; base < n; base += 1024) {
        int i = base + t;
        int v = (i < n) ? cnt[i] : 0;
        buf[t] = v; __syncthreads();
        #pragma unroll
        for (int off = 1; off < 1024; off <<= 1) {
            int tmp = (t >= off) ? buf[t - off] : 0;
            __syncthreads();
            buf[t] += tmp;
            __syncthreads();
        }
        int incl = buf[t];
        if (i < n) rowptr[i] = carry + incl - v;
        int total = buf[1023];
        __syncthreads();
        if (t == 0) carry += total;
        __syncthreads();
    }
    if (t == 0) rowptr[n] = carry;
}

__global__ void copy_i32(const int* __restrict__ s, int* __restrict__ d, int n)
{
    int i = blockIdx.x * blockDim.x + threadIdx.x;
    if (i < n) d[i] = s[i];
}

__global__ void csr_scatter(const int* __restrict__ es, const int* __restrict__ ed,
                            int E, int Etot, int* __restrict__ cursor, int* __restrict__ col)
{
    int k = blockIdx.x * blockDim.x + threadIdx.x;
    if (k >= Etot) return;
    int sn = e_src(es, E, k), dn = e_dst(ed, E, k);
    int pos = atomicAdd(&cursor[dn], 1);
    col[pos] = sn;
}

__global__ void dinv_from_rowptr(const int* __restrict__ rowptr, float* __restrict__ dinv, int n)
{
    int i = blockIdx.x * blockDim.x + threadIdx.x;
    if (i < n) dinv[i] = rsqrtf(fmaxf((float)(rowptr[i + 1] - rowptr[i]), 1.f));
}

__global__ void grp_lb(const int* __restrict__ batch, int N, int G_, int* __restrict__ gptr)
{
    int g = blockIdx.x * blockDim.x + threadIdx.x;
    if (g > G_) return;
    if (g == G_) { gptr[G_] = N; return; }
    int lo = 0, hi = N;
    while (lo < hi) { int mid = (lo + hi) >> 1; if (batch[mid] < g) lo = mid + 1; else hi = mid; }
    gptr[g] = lo;
}

// ============== fused GAT softmax+aggregate (gather, wave per node) ========
template<int C>
__global__ void gat_gather(const int* __restrict__ rowptr, const int* __restrict__ col,
                           const unsigned short* __restrict__ h,
                           const float* __restrict__ als, const float* __restrict__ ald,
                           float* __restrict__ out, int N)
{
    constexpr int V = C / 64;
    int w = (int)(((long long)blockIdx.x * blockDim.x + threadIdx.x) >> 6);
    int lane = threadIdx.x & 63;
    if (w >= N) return;
    int r0 = rowptr[w], r1 = rowptr[w + 1];
    float aldn = ald[w];
    float ssum = 0.f;
    for (int e = r0; e < r1; ++e) {
        float t = als[col[e]] + aldn;
        t = (t >= 0.f) ? t : LEAK * t;
        ssum += expf(t);
    }
    float acc[V] = {};
    for (int e = r0; e < r1; ++e) {
        int sn = col[e];
        float t = als[sn] + aldn;
        t = (t >= 0.f) ? t : LEAK * t;
        float a = expf(t);
        const unsigned short* hp = h + (size_t)sn * C + lane * V;
        if constexpr (V == 4) {
            ushort4 hv = *reinterpret_cast<const ushort4*>(hp);
            acc[0] += bf2f(hv.x) * a; acc[1] += bf2f(hv.y) * a;
            acc[2] += bf2f(hv.z) * a; acc[3] += bf2f(hv.w) * a;
        } else {
            ushort2 hv = *reinterpret_cast<const ushort2*>(hp);
            acc[0] += bf2f(hv.x) * a; acc[1] += bf2f(hv.y) * a;
        }
    }
    float inv = 1.f / fmaxf(ssum, 1e-16f);
    float* op = out + (size_t)w * C + lane * V;
    #pragma unroll
    for (int i = 0; i < V; ++i) op[i] = acc[i] * inv;
}

// ============== GCN gather (wave per node) =================================
template<int C>
__global__ void gcn_gather(const int* __restrict__ rowptr, const int* __restrict__ col,
                           const unsigned short* __restrict__ h,
                           const float* __restrict__ dinv, float* __restrict__ out, int N)
{
    constexpr int V = C / 64;
    int w = (int)(((long long)blockIdx.x * blockDim.x + threadIdx.x) >> 6);
    int lane = threadIdx.x & 63;
    if (w >= N) return;
    int r0 = rowptr[w], r1 = rowptr[w + 1];
    float acc[V] = {};
    for (int e = r0; e < r1; ++e) {
        int sn = col[e];
        float a = dinv[sn];
        const unsigned short* hp = h + (size_t)sn * C + lane * V;
        if constexpr (V == 4) {
            ushort4 hv = *reinterpret_cast<const ushort4*>(hp);
            acc[0] += bf2f(hv.x) * a; acc[1] += bf2f(hv.y) * a;
            acc[2] += bf2f(hv.z) * a; acc[3] += bf2f(hv.w) * a;
        } else {
            ushort2 hv = *reinterpret_cast<const ushort2*>(hp);
            acc[0] += bf2f(hv.x) * a; acc[1] += bf2f(hv.y) * a;
        }
    }
    float dn = dinv[w];
    float* op = out + (size_t)w * C + lane * V;
    #pragma unroll
    for (int i = 0; i < V; ++i) op[i] = acc[i] * dn;
}

// ---- BatchNorm: two-stage high-occupancy stats ----------------------------
// Stage A: grid (1, Y); block covers D cols (float4 groups) x P row-phases.
template<int D>
__global__ __launch_bounds__(256) void bn_part(
    const float* __restrict__ x, float* __restrict__ ps, float* __restrict__ pq,
    int M, int Y)
{
    constexpr int DG = D / 4;
    constexpr int P  = 256 / DG;
    const int t = threadIdx.x;
    const int cg = t % DG, ph = t / DG;
    const int y = blockIdx.y;
    const int rows_per = (M + Y - 1) / Y;
    const int r0 = y * rows_per;
    const int r1 = min(r0 + rows_per, M);
    float s0=0,s1=0,s2=0,s3=0,q0=0,q1=0,q2=0,q3=0;
    for (int r = r0 + ph; r < r1; r += P) {
        float4 v = *reinterpret_cast<const float4*>(x + (size_t)r * D + cg * 4);
        s0+=v.x; s1+=v.y; s2+=v.z; s3+=v.w;
        q0+=v.x*v.x; q1+=v.y*v.y; q2+=v.z*v.z; q3+=v.w*v.w;
    }
    __shared__ float ls[P][D];
    __shared__ float lq[P][D];
    ls[ph][cg*4+0]=s0; ls[ph][cg*4+1]=s1; ls[ph][cg*4+2]=s2; ls[ph][cg*4+3]=s3;
    lq[ph][cg*4+0]=q0; lq[ph][cg*4+1]=q1; lq[ph][cg*4+2]=q2; lq[ph][cg*4+3]=q3;
    __syncthreads();
    if (ph == 0) {
        #pragma unroll
        for (int j = 0; j < 4; ++j) {
            float ss = 0.f, qq = 0.f;
            #pragma unroll
            for (int p = 0; p < P; ++p) { ss += ls[p][cg*4+j]; qq += lq[p][cg*4+j]; }
            ps[(size_t)y * D + cg*4 + j] = ss;
            pq[(size_t)y * D + cg*4 + j] = qq;
        }
    }
}

// Stage B (single block): reduce partials + compute scale/shift (fused bn_fin)
template<int D>
__global__ __launch_bounds__(256) void bn_reduce_fin(
    const float* __restrict__ ps, const float* __restrict__ pq,
    const float* __restrict__ g, const float* __restrict__ b,
    float* __restrict__ scale, float* __restrict__ shift, int Y, float invM)
{
    constexpr int DG = D / 4;
    constexpr int P  = 256 / DG;
    const int t = threadIdx.x;
    const int cg = t % DG, ph = t / DG;
    float s0=0,s1=0,s2=0,s3=0,q0=0,q1=0,q2=0,q3=0;
    for (int y = ph; y < Y; y += P) {
        float4 a = *reinterpret_cast<const float4*>(ps + (size_t)y * D + cg * 4);
        float4 c = *reinterpret_cast<const float4*>(pq + (size_t)y * D + cg * 4);
        s0+=a.x; s1+=a.y; s2+=a.z; s3+=a.w;
        q0+=c.x; q1+=c.y; q2+=c.z; q3+=c.w;
    }
    __shared__ float ls[P][D];
    __shared__ float lq[P][D];
    ls[ph][cg*4+0]=s0; ls[ph][cg*4+1]=s1; ls[ph][cg*4+2]=s2; ls[ph][cg*4+3]=s3;
    lq[ph][cg*4+0]=q0; lq[ph][cg*4+1]=q1; lq[ph][cg*4+2]=q2; lq[ph][cg*4+3]=q3;
    __syncthreads();
    if (ph == 0) {
        #pragma unroll
        for (int j = 0; j < 4; ++j) {
            int c = cg*4 + j;
            float ss = 0.f, qq = 0.f;
            #pragma unroll
            for (int p = 0; p < P; ++p) { ss += ls[p][c]; qq += lq[p][c]; }
            float mu = ss * invM;
            float var = qq * invM - mu * mu;
            float rs = rsqrtf(var + BN_EPS) * g[c];
            scale[c] = rs;
            shift[c] = b[c] - mu * rs;
        }
    }
}

// relu(bn(x)) fp32 in place, vectorized
__global__ void bn_apply_relu4(float* __restrict__ x, const float* __restrict__ scale,
                               const float* __restrict__ shift, int total4, int D4)
{
    int i = blockIdx.x * blockDim.x + threadIdx.x;
    if (i >= total4) return;
    int c4 = (i % D4) * 4;
    float4 v = *reinterpret_cast<const float4*>(x + (size_t)i * 4);
    float4 sc = *reinterpret_cast<const float4*>(scale + c4);
    float4 sh = *reinterpret_cast<const float4*>(shift + c4);
    v.x = fmaxf(v.x * sc.x + sh.x, 0.f);
    v.y = fmaxf(v.y * sc.y + sh.y, 0.f);
    v.z = fmaxf(v.z * sc.z + sh.z, 0.f);
    v.w = fmaxf(v.w * sc.w + sh.w, 0.f);
    *reinterpret_cast<float4*>(x + (size_t)i * 4) = v;
}

// relu(bn(x)) fp32 -> bf16 (dst stride ldd, pre-offset to column block)
__global__ void bn_apply_bf164(const float* __restrict__ x, const float* __restrict__ scale,
                               const float* __restrict__ shift, unsigned short* __restrict__ dst,
                               int total4, int Cb4, int ldd)
{
    int i = blockIdx.x * blockDim.x + threadIdx.x;
    if (i >= total4) return;
    int r = i / Cb4, c4 = (i - r * Cb4) * 4;
    float4 v = *reinterpret_cast<const float4*>(x + (size_t)i * 4);
    float4 sc = *reinterpret_cast<const float4*>(scale + c4);
    float4 sh = *reinterpret_cast<const float4*>(shift + c4);
    ushort4 o;
    o.x = f2bf(fmaxf(v.x * sc.x + sh.x, 0.f));
    o.y = f2bf(fmaxf(v.y * sc.y + sh.y, 0.f));
    o.z = f2bf(fmaxf(v.z * sc.z + sh.z, 0.f));
    o.w = f2bf(fmaxf(v.w * sc.w + sh.w, 0.f));
    *reinterpret_cast<ushort4*>(dst + (size_t)r * ldd + c4) = o;
}

__global__ void conv_f2b4(const float* __restrict__ src, unsigned short* __restrict__ dst, int n4)
{
    int i = blockIdx.x * blockDim.x + threadIdx.x;
    if (i >= n4) return;
    float4 v = *reinterpret_cast<const float4*>(src + (size_t)i * 4);
    ushort4 o = { f2bf(v.x), f2bf(v.y), f2bf(v.z), f2bf(v.w) };
    *reinterpret_cast<ushort4*>(dst + (size_t)i * 4) = o;
}

// ---- Pooling ---------------------------------------------------------------
__global__ __launch_bounds__(256) void pool_gather(const float* __restrict__ h,
                                                   const int* __restrict__ gptr,
                                                   float* __restrict__ z, int G_)
{
    int g = blockIdx.x;
    int c = threadIdx.x;
    int r0 = gptr[g], r1 = gptr[g + 1];
    float s = 0.f, m = 0.f;
    for (int i = r0; i < r1; ++i) {
        float v = h[(size_t)i * 256 + c];
        s += v;
        m = fmaxf(m, v);
    }
    float cnt = fmaxf((float)(r1 - r0), 1.f);
    z[(size_t)g * 640 + c] = s / cnt;
    z[(size_t)g * 640 + 256 + c] = m;
}

__global__ void final_head(const float* __restrict__ f1, const float* __restrict__ Wf2,
                           const float* __restrict__ bf2, float* __restrict__ out, int G_, int D)
{
    int w = (int)(((long long)blockIdx.x * blockDim.x + threadIdx.x) >> 6);
    int lane = threadIdx.x & 63;
    if (w >= G_) return;
    float s = 0.f;
    for (int c = lane; c < D; c += 64) s += f1[(size_t)w * D + c] * Wf2[c];
    #pragma unroll
    for (int off = 32; off; off >>= 1) s += __shfl_down(s, off);
    if (lane == 0) out[w] = 1.f / (1.f + expf(-(s + bf2[0])));
}

__global__ void sentinel(float* __restrict__ out, int n, float v)
{
    int i = blockIdx.x * blockDim.x + threadIdx.x;
    if (i < n) out[i] = v;
}

// ---------------------------------------------------------------------------
extern "C" void kernel_launch(void* const* d_in, const int* in_sizes, int n_in,
                              void* d_out, int out_size, void* d_ws, size_t ws_size,
                              hipStream_t stream)
{
    const float* x    = (const float*)d_in[0];
    const int*   ei   = (const int*)d_in[1];
    const int*   batch= (const int*)d_in[2];
    const float* sfp  = (const float*)d_in[3];
    const float* W1   = (const float*)d_in[4];
    const float* a1s  = (const float*)d_in[5];
    const float* a1d  = (const float*)d_in[6];
    const float* bn1g = (const float*)d_in[8];
    const float* bn1b = (const float*)d_in[9];
    const float* W2   = (const float*)d_in[10];
    const float* a2s  = (const float*)d_in[11];
    const float* a2d  = (const float*)d_in[12];
    const float* bn2g = (const float*)d_in[14];
    const float* bn2b = (const float*)d_in[15];
    const float* Wg   = (const float*)d_in[16];
    const float* bn3g = (const float*)d_in[18];
    const float* bn3b = (const float*)d_in[19];
    const float* Wsm  = (const float*)d_in[20];
    const float* bsm  = (const float*)d_in[21];
    const float* Wf1  = (const float*)d_in[22];
    const float* bnfg = (const float*)d_in[24];
    const float* bnfb = (const float*)d_in[25];
    const float* Wf2  = (const float*)d_in[26];
    const float* bf2  = (const float*)d_in[27];
    float* outp = (float*)d_out;

    const int N    = in_sizes[0] / 64;
    const int E    = in_sizes[1] / 2;
    const int G_   = in_sizes[3] / 128;
    const int Etot = E + N;
    const int* esrc = ei;
    const int* edst = ei + E;
    const int YB = 512;   // bn_part row-splits

    // ---- workspace (fp32-element offsets) ----
    float* ws = (float*)d_ws;
    size_t off = 0;
    float* accA  = ws + off; off += (size_t)N * 256;
    float* h3acc = ws + off; off += (size_t)N * 256;
    unsigned short* o1n = (unsigned short*)(ws + off); off += (size_t)N * 256; // N*512 bf16
    unsigned short* hb  = (unsigned short*)(ws + off); off += (size_t)N * 128; // N*256 bf16
    unsigned short* xb  = (unsigned short*)(ws + off); off += (size_t)N * 32;  // N*64 bf16
    float* als = ws + off; off += N;
    float* ald = ws + off; off += N;
    float* dinv= ws + off; off += N;
    float* bsc = ws + off; off += 1024;
    float* bsh = ws + off; off += 1024;
    float* ps  = ws + off; off += (size_t)YB * 256;
    float* pq  = ws + off; off += (size_t)YB * 256;
    float* z   = ws + off; off += (size_t)G_ * 640;
    float* f1  = ws + off; off += (size_t)G_ * 128;
    int* rowptr = (int*)(ws + off); off += (size_t)(N + 1);
    int* colc   = (int*)(ws + off); off += (size_t)Etot;
    int* cursor = (int*)(ws + off); off += (size_t)N;
    int* gptr   = (int*)(ws + off); off += (size_t)(G_ + 1);
    unsigned short* W1t = (unsigned short*)(ws + off); off += 64 * 512 / 2;
    unsigned short* W2t = (unsigned short*)(ws + off); off += 512 * 1024 / 2;
    unsigned short* Wgt = (unsigned short*)(ws + off); off += 1024 * 256 / 2;
    size_t need = off * 4;
    if (ws_size < need) {
        sentinel<<<cdiv(out_size, 256), 256, 0, stream>>>(outp, out_size, (float)(ws_size >> 20));
        return;
    }

    const int BLK = 256;
    dim3 blk(BLK);

    // ============ weight prep (bf16 + transpose) + x cast ===================
    convT<<<cdiv(64 * 512, BLK), blk, 0, stream>>>(W1, W1t, 64, 512);
    convT<<<cdiv(512 * 1024, BLK), blk, 0, stream>>>(W2, W2t, 512, 1024);
    convT<<<cdiv(1024 * 256, BLK), blk, 0, stream>>>(Wg, Wgt, 1024, 256);
    conv_f2b4<<<cdiv((long long)N * 16, BLK), blk, 0, stream>>>(x, xb, N * 16);

    // ================= build CSR (dst -> src) + group bounds ================
    fill_i32<<<cdiv(N, BLK), blk, 0, stream>>>(cursor, 1, N);   // self-loops
    hist_dst<<<cdiv(E, BLK), blk, 0, stream>>>(edst, E, cursor);
    scan_excl<<<1, 1024, 0, stream>>>(cursor, rowptr, N);
    copy_i32<<<cdiv(N, BLK), blk, 0, stream>>>(rowptr, cursor, N);
    csr_scatter<<<cdiv(Etot, BLK), blk, 0, stream>>>(esrc, edst, E, Etot, cursor, colc);
    dinv_from_rowptr<<<cdiv(N, BLK), blk, 0, stream>>>(rowptr, dinv, N);
    grp_lb<<<cdiv(G_ + 1, BLK), blk, 0, stream>>>(batch, N, G_, gptr);

    // ================= GAT layer 1 (64 -> 4 heads x 128) ====================
    for (int hh = 0; hh < 4; ++hh) {
        { dim3 g(1, cdiv(N, 128));
          gemm_mfma<unsigned short, false><<<g, blk, 0, stream>>>(
              xb, W1t + (size_t)hh * 128 * 64, hb, N, 64, 64, 64, 128); }
        attn_logits1<<<cdiv((long long)N * 64, BLK), blk, 0, stream>>>(
            hb, a1s + hh * 128, a1d + hh * 128, als, ald, N, 128);
        gat_gather<128><<<cdiv((long long)N * 64, BLK), blk, 0, stream>>>(
            rowptr, colc, hb, als, ald, accA, N);
        { dim3 g(1, YB); bn_part<128><<<g, blk, 0, stream>>>(accA, ps, pq, N, YB); }
        bn_reduce_fin<128><<<1, blk, 0, stream>>>(ps, pq, bn1g + hh * 128, bn1b + hh * 128,
                                                  bsc, bsh, YB, 1.f / N);
        bn_apply_bf164<<<cdiv((long long)N * 32, BLK), blk, 0, stream>>>(
            accA, bsc, bsh, o1n + hh * 128, N * 32, 32, 512);
    }

    // ======= GAT layer 2 (512 -> 4 heads x 256) + fused GCN GEMM ===========
    for (int hh = 0; hh < 4; ++hh) {
        { dim3 g(2, cdiv(N, 128));
          gemm_mfma<unsigned short, false><<<g, blk, 0, stream>>>(
              o1n, W2t + (size_t)hh * 256 * 512, hb, N, 512, 512, 512, 256); }
        attn_logits1<<<cdiv((long long)N * 64, BLK), blk, 0, stream>>>(
            hb, a2s + hh * 256, a2d + hh * 256, als, ald, N, 256);
        gat_gather<256><<<cdiv((long long)N * 64, BLK), blk, 0, stream>>>(
            rowptr, colc, hb, als, ald, accA, N);
        { dim3 g(1, YB); bn_part<256><<<g, blk, 0, stream>>>(accA, ps, pq, N, YB); }
        bn_reduce_fin<256><<<1, blk, 0, stream>>>(ps, pq, bn2g + hh * 256, bn2b + hh * 256,
                                                  bsc, bsh, YB, 1.f / N);
        bn_apply_bf164<<<cdiv((long long)N * 64, BLK), blk, 0, stream>>>(
            accA, bsc, bsh, hb, N * 64, 64, 256);
        { dim3 g(2, cdiv(N, 128));
          if (hh == 0)
              gemm_mfma<float, false><<<g, blk, 0, stream>>>(
                  hb, Wgt + (size_t)hh * 256, h3acc, N, 256, 256, 1024, 256);
          else
              gemm_mfma<float, true><<<g, blk, 0, stream>>>(
                  hb, Wgt + (size_t)hh * 256, h3acc, N, 256, 256, 1024, 256); }
    }

    // ================= GCN aggregation + BN3 ================================
    conv_f2b4<<<cdiv((long long)N * 64, BLK), blk, 0, stream>>>(h3acc, hb, N * 64);
    gcn_gather<256><<<cdiv((long long)N * 64, BLK), blk, 0, stream>>>(
        rowptr, colc, hb, dinv, accA, N);
    { dim3 g(1, YB); bn_part<256><<<g, blk, 0, stream>>>(accA, ps, pq, N, YB); }
    bn_reduce_fin<256><<<1, blk, 0, stream>>>(ps, pq, bn3g, bn3b, bsc, bsh, YB, 1.f / N);
    bn_apply_relu4<<<cdiv((long long)N * 64, BLK), blk, 0, stream>>>(accA, bsc, bsh, N * 64, 64);

    // ================= Pooling ==============================================
    pool_gather<<<G_, blk, 0, stream>>>(accA, gptr, z, G_);

    // solvent MLP -> z[:, 512:640]
    { dim3 g(2, cdiv(G_, 64));
      gemm_t<float, float, false, true><<<g, blk, 0, stream>>>(
          sfp, Wsm, bsm, z + 512, G_, 128, 128, 128, 128, 640); }

    // ================= Head =================================================
    { dim3 g(2, cdiv(G_, 64));
      gemm_t<float, float, false, false><<<g, blk, 0, stream>>>(
          z, Wf1, nullptr, f1, G_, 640, 128, 640, 128, 128); }
    { dim3 g(1, YB); bn_part<128><<<g, blk, 0, stream>>>(f1, ps, pq, G_, YB); }
    bn_reduce_fin<128><<<1, blk, 0, stream>>>(ps, pq, bnfg, bnfb, bsc, bsh, YB, 1.f / G_);
    bn_apply_relu4<<<cdiv((long long)G_ * 32, BLK), blk, 0, stream>>>(f1, bsc, bsh, G_ * 32, 32);
    final_head<<<cdiv((long long)G_ * 64, BLK), blk, 0, stream>>>(f1, Wf2, bf2, outp, G_, 128);
}

// Round 6
// 1503.326 us; speedup vs baseline: 6.2706x; 1.2767x over previous
//
#include <hip/hip_runtime.h>
#include <cmath>

#define LEAK 0.2f
#define BN_EPS 1e-5f

static inline int cdiv(long long a, long long b){ return (int)((a + b - 1) / b); }

typedef __attribute__((ext_vector_type(8))) short bf16x8;
typedef __attribute__((ext_vector_type(4))) float f32x4;

// ---- bf16 helpers (manual, RNE) -------------------------------------------
__device__ __forceinline__ float bf2f(unsigned short u){
    return __uint_as_float(((unsigned int)u) << 16);
}
__device__ __forceinline__ unsigned short f2bf(float f){
    unsigned int u = __float_as_uint(f);
    u += 0x7FFFu + ((u >> 16) & 1u);
    return (unsigned short)(u >> 16);
}
__device__ __forceinline__ float ldA(const float* p){ return *p; }
__device__ __forceinline__ float ldA(const unsigned short* p){ return bf2f(*p); }
__device__ __forceinline__ void stC(float* p, float v){ *p = v; }
__device__ __forceinline__ void stC(unsigned short* p, float v){ *p = f2bf(v); }

// ---------------------------------------------------------------------------
// MFMA bf16 GEMM (128x128 tile, BK=32, 4 waves x 4x4 16x16x32 MFMAs)
// ---------------------------------------------------------------------------
template<typename TC, bool ACC>
__global__ __launch_bounds__(256) void gemm_mfma(
    const unsigned short* __restrict__ A, const unsigned short* __restrict__ Bt,
    TC* __restrict__ C, int M, int K, int lda, int ldb, int ldc)
{
    __shared__ unsigned short As[128 * 40];
    __shared__ unsigned short Bs[128 * 40];
    const int t = threadIdx.x;
    const int row0 = blockIdx.y * 128, col0 = blockIdx.x * 128;
    const int lane = t & 63, wv = t >> 6;
    const int wm = (wv >> 1) << 6, wn = (wv & 1) << 6;
    const int lm = lane & 15, lq = lane >> 4;

    f32x4 acc[4][4] = {};

    for (int k0 = 0; k0 < K; k0 += 32) {
        #pragma unroll
        for (int q = t; q < 512; q += 256) {
            int r = q >> 2, c8 = (q & 3) << 3;
            int gr = row0 + r; if (gr >= M) gr = M - 1;
            bf16x8 v = *(const bf16x8*)(A + (size_t)gr * lda + k0 + c8);
            *(bf16x8*)&As[r * 40 + c8] = v;
        }
        #pragma unroll
        for (int q = t; q < 512; q += 256) {
            int r = q >> 2, c8 = (q & 3) << 3;
            bf16x8 v = *(const bf16x8*)(Bt + (size_t)(col0 + r) * ldb + k0 + c8);
            *(bf16x8*)&Bs[r * 40 + c8] = v;
        }
        __syncthreads();

        bf16x8 af[4], bfr[4];
        #pragma unroll
        for (int mi = 0; mi < 4; ++mi)
            af[mi] = *(const bf16x8*)&As[(wm + mi * 16 + lm) * 40 + lq * 8];
        #pragma unroll
        for (int ni = 0; ni < 4; ++ni)
            bfr[ni] = *(const bf16x8*)&Bs[(wn + ni * 16 + lm) * 40 + lq * 8];
        #pragma unroll
        for (int mi = 0; mi < 4; ++mi)
            #pragma unroll
            for (int ni = 0; ni < 4; ++ni)
                acc[mi][ni] = __builtin_amdgcn_mfma_f32_16x16x32_bf16(
                    af[mi], bfr[ni], acc[mi][ni], 0, 0, 0);
        __syncthreads();
    }

    #pragma unroll
    for (int mi = 0; mi < 4; ++mi) {
        int row_b = row0 + wm + mi * 16 + lq * 4;
        #pragma unroll
        for (int ni = 0; ni < 4; ++ni) {
            int col = col0 + wn + ni * 16 + lm;
            #pragma unroll
            for (int r = 0; r < 4; ++r) {
                int row = row_b + r;
                if (row < M) {
                    float v = acc[mi][ni][r];
                    if constexpr (ACC) v += reinterpret_cast<const float*>(C)[(size_t)row * ldc + col];
                    stC(&C[(size_t)row * ldc + col], v);
                }
            }
        }
    }
}

// convert fp32 W[K,Nc] -> bf16 W^T[Nc,K]
__global__ void convT(const float* __restrict__ W, unsigned short* __restrict__ Wt, int K, int Nc)
{
    int i = blockIdx.x * blockDim.x + threadIdx.x;
    if (i >= K * Nc) return;
    int k = i / Nc, n = i - k * Nc;
    Wt[(size_t)n * K + k] = f2bf(W[i]);
}

// ---------------------------------------------------------------------------
// fp32 tiled GEMM (small head GEMMs only)
// ---------------------------------------------------------------------------
template<typename TA, typename TC, bool ACC, bool RELU>
__global__ __launch_bounds__(256) void gemm_t(
    const TA* __restrict__ A, const float* __restrict__ B,
    const float* __restrict__ bias, TC* __restrict__ C,
    int M, int K, int Nc, int lda, int ldb, int ldc)
{
    __shared__ float As[16][65];
    __shared__ float Bs[16][64];
    const int tid = threadIdx.x;
    const int tx = tid & 15, ty = tid >> 4;
    const int row0 = blockIdx.y * 64, col0 = blockIdx.x * 64;
    float acc[4][4] = {};

    for (int k0 = 0; k0 < K; k0 += 16) {
        #pragma unroll
        for (int i = 0; i < 4; ++i) {
            int f = tid * 4 + i, r = f >> 4, c = f & 15;
            int gr = row0 + r;
            As[c][r] = (gr < M) ? ldA(&A[(size_t)gr * lda + k0 + c]) : 0.f;
        }
        #pragma unroll
        for (int i = 0; i < 4; ++i) {
            int f = tid * 4 + i, r = f >> 6, c = f & 63;
            int gc = col0 + c;
            Bs[r][c] = (gc < Nc) ? B[(size_t)(k0 + r) * ldb + gc] : 0.f;
        }
        __syncthreads();
        #pragma unroll
        for (int kk = 0; kk < 16; ++kk) {
            float a[4], b[4];
            #pragma unroll
            for (int i = 0; i < 4; ++i) a[i] = As[kk][ty + 16 * i];
            #pragma unroll
            for (int j = 0; j < 4; ++j) b[j] = Bs[kk][tx + 16 * j];
            #pragma unroll
            for (int i = 0; i < 4; ++i)
                #pragma unroll
                for (int j = 0; j < 4; ++j)
                    acc[i][j] += a[i] * b[j];
        }
        __syncthreads();
    }
    #pragma unroll
    for (int i = 0; i < 4; ++i) {
        int r = row0 + ty + 16 * i;
        if (r >= M) continue;
        #pragma unroll
        for (int j = 0; j < 4; ++j) {
            int c = col0 + tx + 16 * j;
            if (c >= Nc) continue;
            float v = acc[i][j];
            if (bias) v += bias[c];
            if constexpr (ACC) v += reinterpret_cast<const float*>(C)[(size_t)r * ldc + c];
            if constexpr (RELU) v = fmaxf(v, 0.f);
            stC(&C[(size_t)r * ldc + c], v);
        }
    }
}

// ---- attention logits, layer 2 (single head): wave per node ----------------
__global__ void attn_logits1(const unsigned short* __restrict__ h,
                             const float* __restrict__ avs, const float* __restrict__ avd,
                             float* __restrict__ als, float* __restrict__ ald, int N, int C)
{
    int w = (int)(((long long)blockIdx.x * blockDim.x + threadIdx.x) >> 6);
    int lane = threadIdx.x & 63;
    if (w >= N) return;
    const unsigned short* hp = h + (size_t)w * C;
    float s = 0.f, d = 0.f;
    for (int c = lane; c < C; c += 64) {
        float v = bf2f(hp[c]);
        s += v * avs[c];
        d += v * avd[c];
    }
    #pragma unroll
    for (int off = 32; off; off >>= 1) {
        s += __shfl_down(s, off);
        d += __shfl_down(d, off);
    }
    if (lane == 0) { als[w] = s; ald[w] = d; }
}

// ---- attention logits, layer 1 (all 4 heads): wave per (node,head) ---------
// h: [N][512] bf16 (head h occupies cols h*128..+128); als/ald: [N*4] (node*4+head)
__global__ void attn_logits4(const unsigned short* __restrict__ h,
                             const float* __restrict__ avs, const float* __restrict__ avd,
                             float* __restrict__ als, float* __restrict__ ald, int N)
{
    int w = (int)(((long long)blockIdx.x * blockDim.x + threadIdx.x) >> 6);
    int lane = threadIdx.x & 63;
    if (w >= N * 4) return;
    int node = w >> 2, head = w & 3;
    const unsigned short* hp = h + (size_t)node * 512 + head * 128 + lane * 2;
    const float* as = avs + head * 128 + lane * 2;
    const float* ad = avd + head * 128 + lane * 2;
    ushort2 hv = *reinterpret_cast<const ushort2*>(hp);
    float v0 = bf2f(hv.x), v1 = bf2f(hv.y);
    float s = v0 * as[0] + v1 * as[1];
    float d = v0 * ad[0] + v1 * ad[1];
    #pragma unroll
    for (int off = 32; off; off >>= 1) {
        s += __shfl_down(s, off);
        d += __shfl_down(d, off);
    }
    if (lane == 0) { als[w] = s; ald[w] = d; }
}

// ============================ CSR build ====================================
__device__ __forceinline__ int e_src(const int* es, int E, int k){ return k < E ? es[k] : k - E; }
__device__ __forceinline__ int e_dst(const int* ed, int E, int k){ return k < E ? ed[k] : k - E; }

__global__ void fill_i32(int* __restrict__ p, int v, int n)
{
    int i = blockIdx.x * blockDim.x + threadIdx.x;
    if (i < n) p[i] = v;
}

__global__ void hist_dst(const int* __restrict__ ed, int E, int* __restrict__ cnt)
{
    int k = blockIdx.x * blockDim.x + threadIdx.x;
    if (k < E) atomicAdd(&cnt[ed[k]], 1);
}

// chunked single-block exclusive scan: thread t owns a contiguous chunk
__global__ __launch_bounds__(1024) void scan_excl2(const int* __restrict__ cnt,
                                                   int* __restrict__ rowptr, int n)
{
    __shared__ int tsum[1024];
    const int t = threadIdx.x;
    const int chunk = (n + 1023) >> 10;
    const int b0 = t * chunk;
    const int b1 = min(b0 + chunk, n);
    int s = 0;
    for (int i = b0; i < b1; ++i) s += cnt[i];
    tsum[t] = s;
    __syncthreads();
    #pragma unroll
    for (int off = 1; off < 1024; off <<= 1) {
        int v = (t >= off) ? tsum[t - off] : 0;
        __syncthreads();
        tsum[t] += v;
        __syncthreads();
    }
    int base = (t > 0) ? tsum[t - 1] : 0;
    for (int i = b0; i < b1; ++i) { rowptr[i] = base; base += cnt[i]; }
    if (t == 1023) rowptr[n] = tsum[1023];
}

__global__ void copy_i32(const int* __restrict__ s, int* __restrict__ d, int n)
{
    int i = blockIdx.x * blockDim.x + threadIdx.x;
    if (i < n) d[i] = s[i];
}

__global__ void csr_scatter(const int* __restrict__ es, const int* __restrict__ ed,
                            int E, int Etot, int* __restrict__ cursor, int* __restrict__ col)
{
    int k = blockIdx.x * blockDim.x + threadIdx.x;
    if (k >= Etot) return;
    int sn = e_src(es, E, k), dn = e_dst(ed, E, k);
    int pos = atomicAdd(&cursor[dn], 1);
    col[pos] = sn;
}

__global__ void dinv_from_rowptr(const int* __restrict__ rowptr, float* __restrict__ dinv, int n)
{
    int i = blockIdx.x * blockDim.x + threadIdx.x;
    if (i < n) dinv[i] = rsqrtf(fmaxf((float)(rowptr[i + 1] - rowptr[i]), 1.f));
}

__global__ void grp_lb(const int* __restrict__ batch, int N, int G_, int* __restrict__ gptr)
{
    int g = blockIdx.x * blockDim.x + threadIdx.x;
    if (g > G_) return;
    if (g == G_) { gptr[G_] = N; return; }
    int lo = 0, hi = N;
    while (lo < hi) { int mid = (lo + hi) >> 1; if (batch[mid] < g) lo = mid + 1; else hi = mid; }
    gptr[g] = lo;
}

// ====== layer-1 fused GAT softmax+aggregate, all heads; wave per (node,head)
// single pass: out = sum(exp_e * h_src) / sum(exp_e)
__global__ void gat_gather4(const int* __restrict__ rowptr, const int* __restrict__ col,
                            const unsigned short* __restrict__ h,
                            const float* __restrict__ als, const float* __restrict__ ald,
                            float* __restrict__ out, int N)
{
    int w = (int)(((long long)blockIdx.x * blockDim.x + threadIdx.x) >> 6);
    int lane = threadIdx.x & 63;
    if (w >= N * 4) return;
    int node = w >> 2, head = w & 3;
    int r0 = rowptr[node], r1 = rowptr[node + 1];
    float aldn = ald[w];
    float ssum = 0.f;
    float a0 = 0.f, a1 = 0.f;
    for (int e = r0; e < r1; ++e) {
        int sn = col[e];
        float t = als[sn * 4 + head] + aldn;
        t = (t >= 0.f) ? t : LEAK * t;
        float a = expf(t);
        ssum += a;
        ushort2 hv = *reinterpret_cast<const ushort2*>(h + (size_t)sn * 512 + head * 128 + lane * 2);
        a0 += bf2f(hv.x) * a;
        a1 += bf2f(hv.y) * a;
    }
    float inv = 1.f / fmaxf(ssum, 1e-16f);
    float* op = out + (size_t)node * 512 + head * 128 + lane * 2;
    op[0] = a0 * inv;
    op[1] = a1 * inv;
}

// ====== layer-2 fused GAT gather, single head C=256; wave per node ==========
__global__ void gat_gather256(const int* __restrict__ rowptr, const int* __restrict__ col,
                              const unsigned short* __restrict__ h,
                              const float* __restrict__ als, const float* __restrict__ ald,
                              float* __restrict__ out, int N)
{
    int w = (int)(((long long)blockIdx.x * blockDim.x + threadIdx.x) >> 6);
    int lane = threadIdx.x & 63;
    if (w >= N) return;
    int r0 = rowptr[w], r1 = rowptr[w + 1];
    float aldn = ald[w];
    float ssum = 0.f;
    float a0 = 0.f, a1 = 0.f, a2 = 0.f, a3 = 0.f;
    for (int e = r0; e < r1; ++e) {
        int sn = col[e];
        float t = als[sn] + aldn;
        t = (t >= 0.f) ? t : LEAK * t;
        float a = expf(t);
        ssum += a;
        ushort4 hv = *reinterpret_cast<const ushort4*>(h + (size_t)sn * 256 + lane * 4);
        a0 += bf2f(hv.x) * a; a1 += bf2f(hv.y) * a;
        a2 += bf2f(hv.z) * a; a3 += bf2f(hv.w) * a;
    }
    float inv = 1.f / fmaxf(ssum, 1e-16f);
    float* op = out + (size_t)w * 256 + lane * 4;
    op[0] = a0 * inv; op[1] = a1 * inv; op[2] = a2 * inv; op[3] = a3 * inv;
}

// ====== GCN gather, fp32 input (C=256); wave per node =======================
__global__ void gcn_gather_f32(const int* __restrict__ rowptr, const int* __restrict__ col,
                               const float* __restrict__ h,
                               const float* __restrict__ dinv, float* __restrict__ out, int N)
{
    int w = (int)(((long long)blockIdx.x * blockDim.x + threadIdx.x) >> 6);
    int lane = threadIdx.x & 63;
    if (w >= N) return;
    int r0 = rowptr[w], r1 = rowptr[w + 1];
    float a0 = 0.f, a1 = 0.f, a2 = 0.f, a3 = 0.f;
    for (int e = r0; e < r1; ++e) {
        int sn = col[e];
        float a = dinv[sn];
        float4 hv = *reinterpret_cast<const float4*>(h + (size_t)sn * 256 + lane * 4);
        a0 += hv.x * a; a1 += hv.y * a; a2 += hv.z * a; a3 += hv.w * a;
    }
    float dn = dinv[w];
    float* op = out + (size_t)w * 256 + lane * 4;
    op[0] = a0 * dn; op[1] = a1 * dn; op[2] = a2 * dn; op[3] = a3 * dn;
}

// ---- BatchNorm: two-stage high-occupancy stats ----------------------------
template<int D>
__global__ __launch_bounds__(256) void bn_part(
    const float* __restrict__ x, float* __restrict__ ps, float* __restrict__ pq,
    int M, int Y)
{
    constexpr int DG = D / 4;
    constexpr int P  = 256 / DG;
    const int t = threadIdx.x;
    const int cg = t % DG, ph = t / DG;
    const int y = blockIdx.y;
    const int rows_per = (M + Y - 1) / Y;
    const int r0 = y * rows_per;
    const int r1 = min(r0 + rows_per, M);
    float s0=0,s1=0,s2=0,s3=0,q0=0,q1=0,q2=0,q3=0;
    for (int r = r0 + ph; r < r1; r += P) {
        float4 v = *reinterpret_cast<const float4*>(x + (size_t)r * D + cg * 4);
        s0+=v.x; s1+=v.y; s2+=v.z; s3+=v.w;
        q0+=v.x*v.x; q1+=v.y*v.y; q2+=v.z*v.z; q3+=v.w*v.w;
    }
    __shared__ float ls[P][D];
    __shared__ float lq[P][D];
    ls[ph][cg*4+0]=s0; ls[ph][cg*4+1]=s1; ls[ph][cg*4+2]=s2; ls[ph][cg*4+3]=s3;
    lq[ph][cg*4+0]=q0; lq[ph][cg*4+1]=q1; lq[ph][cg*4+2]=q2; lq[ph][cg*4+3]=q3;
    __syncthreads();
    if (ph == 0) {
        #pragma unroll
        for (int j = 0; j < 4; ++j) {
            float ss = 0.f, qq = 0.f;
            #pragma unroll
            for (int p = 0; p < P; ++p) { ss += ls[p][cg*4+j]; qq += lq[p][cg*4+j]; }
            ps[(size_t)y * D + cg*4 + j] = ss;
            pq[(size_t)y * D + cg*4 + j] = qq;
        }
    }
}

template<int D>
__global__ __launch_bounds__(256) void bn_reduce_fin(
    const float* __restrict__ ps, const float* __restrict__ pq,
    const float* __restrict__ g, const float* __restrict__ b,
    float* __restrict__ scale, float* __restrict__ shift, int Y, float invM)
{
    constexpr int DG = D / 4;
    constexpr int P  = 256 / DG;
    const int t = threadIdx.x;
    const int cg = t % DG, ph = t / DG;
    float s0=0,s1=0,s2=0,s3=0,q0=0,q1=0,q2=0,q3=0;
    for (int y = ph; y < Y; y += P) {
        float4 a = *reinterpret_cast<const float4*>(ps + (size_t)y * D + cg * 4);
        float4 c = *reinterpret_cast<const float4*>(pq + (size_t)y * D + cg * 4);
        s0+=a.x; s1+=a.y; s2+=a.z; s3+=a.w;
        q0+=c.x; q1+=c.y; q2+=c.z; q3+=c.w;
    }
    __shared__ float ls[P][D];
    __shared__ float lq[P][D];
    ls[ph][cg*4+0]=s0; ls[ph][cg*4+1]=s1; ls[ph][cg*4+2]=s2; ls[ph][cg*4+3]=s3;
    lq[ph][cg*4+0]=q0; lq[ph][cg*4+1]=q1; lq[ph][cg*4+2]=q2; lq[ph][cg*4+3]=q3;
    __syncthreads();
    if (ph == 0) {
        #pragma unroll
        for (int j = 0; j < 4; ++j) {
            int c = cg*4 + j;
            float ss = 0.f, qq = 0.f;
            #pragma unroll
            for (int p = 0; p < P; ++p) { ss += ls[p][c]; qq += lq[p][c]; }
            float mu = ss * invM;
            float var = qq * invM - mu * mu;
            float rs = rsqrtf(var + BN_EPS) * g[c];
            scale[c] = rs;
            shift[c] = b[c] - mu * rs;
        }
    }
}

// relu(bn(x)) fp32 -> bf16 (dst stride ldd)
__global__ void bn_apply_bf164(const float* __restrict__ x, const float* __restrict__ scale,
                               const float* __restrict__ shift, unsigned short* __restrict__ dst,
                               int total4, int Cb4, int ldd)
{
    int i = blockIdx.x * blockDim.x + threadIdx.x;
    if (i >= total4) return;
    int r = i / Cb4, c4 = (i - r * Cb4) * 4;
    float4 v = *reinterpret_cast<const float4*>(x + (size_t)i * 4);
    float4 sc = *reinterpret_cast<const float4*>(scale + c4);
    float4 sh = *reinterpret_cast<const float4*>(shift + c4);
    ushort4 o;
    o.x = f2bf(fmaxf(v.x * sc.x + sh.x, 0.f));
    o.y = f2bf(fmaxf(v.y * sc.y + sh.y, 0.f));
    o.z = f2bf(fmaxf(v.z * sc.z + sh.z, 0.f));
    o.w = f2bf(fmaxf(v.w * sc.w + sh.w, 0.f));
    *reinterpret_cast<ushort4*>(dst + (size_t)r * ldd + c4) = o;
}

__global__ void conv_f2b4(const float* __restrict__ src, unsigned short* __restrict__ dst, int n4)
{
    int i = blockIdx.x * blockDim.x + threadIdx.x;
    if (i >= n4) return;
    float4 v = *reinterpret_cast<const float4*>(src + (size_t)i * 4);
    ushort4 o = { f2bf(v.x), f2bf(v.y), f2bf(v.z), f2bf(v.w) };
    *reinterpret_cast<ushort4*>(dst + (size_t)i * 4) = o;
}

// ---- Pooling with fused BN3 apply+relu ------------------------------------
__global__ __launch_bounds__(256) void pool_gather_bn(const float* __restrict__ h,
                                                      const float* __restrict__ scale,
                                                      const float* __restrict__ shift,
                                                      const int* __restrict__ gptr,
                                                      float* __restrict__ z, int G_)
{
    int g = blockIdx.x;
    int c = threadIdx.x;
    int r0 = gptr[g], r1 = gptr[g + 1];
    float sc = scale[c], sh = shift[c];
    float s = 0.f, m = 0.f;
    for (int i = r0; i < r1; ++i) {
        float v = fmaxf(h[(size_t)i * 256 + c] * sc + sh, 0.f);
        s += v;
        m = fmaxf(m, v);
    }
    float cnt = fmaxf((float)(r1 - r0), 1.f);
    z[(size_t)g * 640 + c] = s / cnt;
    z[(size_t)g * 640 + 256 + c] = m;
}

// ---- final head with fused BNf apply+relu ---------------------------------
__global__ void final_head_bn(const float* __restrict__ f1,
                              const float* __restrict__ scale, const float* __restrict__ shift,
                              const float* __restrict__ Wf2, const float* __restrict__ bf2,
                              float* __restrict__ out, int G_)
{
    int w = (int)(((long long)blockIdx.x * blockDim.x + threadIdx.x) >> 6);
    int lane = threadIdx.x & 63;
    if (w >= G_) return;
    float s = 0.f;
    #pragma unroll
    for (int q = 0; q < 2; ++q) {
        int c = lane + q * 64;
        float v = fmaxf(f1[(size_t)w * 128 + c] * scale[c] + shift[c], 0.f);
        s += v * Wf2[c];
    }
    #pragma unroll
    for (int off = 32; off; off >>= 1) s += __shfl_down(s, off);
    if (lane == 0) out[w] = 1.f / (1.f + expf(-(s + bf2[0])));
}

__global__ void sentinel(float* __restrict__ out, int n, float v)
{
    int i = blockIdx.x * blockDim.x + threadIdx.x;
    if (i < n) out[i] = v;
}

// ---------------------------------------------------------------------------
extern "C" void kernel_launch(void* const* d_in, const int* in_sizes, int n_in,
                              void* d_out, int out_size, void* d_ws, size_t ws_size,
                              hipStream_t stream)
{
    const float* x    = (const float*)d_in[0];
    const int*   ei   = (const int*)d_in[1];
    const int*   batch= (const int*)d_in[2];
    const float* sfp  = (const float*)d_in[3];
    const float* W1   = (const float*)d_in[4];
    const float* a1s  = (const float*)d_in[5];
    const float* a1d  = (const float*)d_in[6];
    const float* bn1g = (const float*)d_in[8];
    const float* bn1b = (const float*)d_in[9];
    const float* W2   = (const float*)d_in[10];
    const float* a2s  = (const float*)d_in[11];
    const float* a2d  = (const float*)d_in[12];
    const float* bn2g = (const float*)d_in[14];
    const float* bn2b = (const float*)d_in[15];
    const float* Wg   = (const float*)d_in[16];
    const float* bn3g = (const float*)d_in[18];
    const float* bn3b = (const float*)d_in[19];
    const float* Wsm  = (const float*)d_in[20];
    const float* bsm  = (const float*)d_in[21];
    const float* Wf1  = (const float*)d_in[22];
    const float* bnfg = (const float*)d_in[24];
    const float* bnfb = (const float*)d_in[25];
    const float* Wf2  = (const float*)d_in[26];
    const float* bf2  = (const float*)d_in[27];
    float* outp = (float*)d_out;

    const int N    = in_sizes[0] / 64;
    const int E    = in_sizes[1] / 2;
    const int G_   = in_sizes[3] / 128;
    const int Etot = E + N;
    const int* esrc = ei;
    const int* edst = ei + E;
    const int YB = 256;   // bn_part row-splits

    // ---- workspace (fp32-element offsets) ----
    // accA+h3acc are contiguous: together they form accL (N x 512 fp32) for layer-1.
    // R1 holds layer-1 pre-BN h1 (bf16), later overwritten by o1n (post-BN bf16).
    float* ws = (float*)d_ws;
    size_t off = 0;
    float* accA  = ws + off; off += (size_t)N * 256;
    float* h3acc = ws + off; off += (size_t)N * 256;
    float* accL  = accA;                                     // N x 512 fp32 (layer 1)
    unsigned short* R1 = (unsigned short*)(ws + off); off += (size_t)N * 256; // N*512 bf16
    unsigned short* h1b = R1;       // layer-1 pre-BN
    unsigned short* o1n = R1;       // layer-1 post-BN (overwrites h1b)
    unsigned short* hb  = (unsigned short*)(ws + off); off += (size_t)N * 128; // N*256 bf16
    unsigned short* xb  = (unsigned short*)(ws + off); off += (size_t)N * 32;  // N*64 bf16
    float* als4 = ws + off; off += (size_t)N * 4;
    float* ald4 = ws + off; off += (size_t)N * 4;
    float* dinv = ws + off; off += N;
    float* bsc = ws + off; off += 1024;
    float* bsh = ws + off; off += 1024;
    float* ps  = ws + off; off += (size_t)YB * 512;
    float* pq  = ws + off; off += (size_t)YB * 512;
    float* z   = ws + off; off += (size_t)G_ * 640;
    float* f1  = ws + off; off += (size_t)G_ * 128;
    int* rowptr = (int*)(ws + off); off += (size_t)(N + 1);
    int* colc   = (int*)(ws + off); off += (size_t)Etot;
    int* gptr   = (int*)(ws + off); off += (size_t)(G_ + 1);
    unsigned short* W1t = (unsigned short*)(ws + off); off += 64 * 512 / 2;
    unsigned short* W2t = (unsigned short*)(ws + off); off += 512 * 1024 / 2;
    unsigned short* Wgt = (unsigned short*)(ws + off); off += 1024 * 256 / 2;
    int* cursor = (int*)als4;   // alias: cursor dead before als4 is written
    size_t need = off * 4;
    if (ws_size < need) {
        sentinel<<<cdiv(out_size, 256), 256, 0, stream>>>(outp, out_size, (float)(ws_size >> 20));
        return;
    }

    const int BLK = 256;
    dim3 blk(BLK);

    // ============ weight prep (bf16 + transpose) + x cast ===================
    convT<<<cdiv(64 * 512, BLK), blk, 0, stream>>>(W1, W1t, 64, 512);
    convT<<<cdiv(512 * 1024, BLK), blk, 0, stream>>>(W2, W2t, 512, 1024);
    convT<<<cdiv(1024 * 256, BLK), blk, 0, stream>>>(Wg, Wgt, 1024, 256);
    conv_f2b4<<<cdiv((long long)N * 16, BLK), blk, 0, stream>>>(x, xb, N * 16);

    // ================= build CSR (dst -> src) + group bounds ================
    fill_i32<<<cdiv(N, BLK), blk, 0, stream>>>(cursor, 1, N);   // self-loops
    hist_dst<<<cdiv(E, BLK), blk, 0, stream>>>(edst, E, cursor);
    scan_excl2<<<1, 1024, 0, stream>>>(cursor, rowptr, N);
    copy_i32<<<cdiv(N, BLK), blk, 0, stream>>>(rowptr, cursor, N);
    csr_scatter<<<cdiv(Etot, BLK), blk, 0, stream>>>(esrc, edst, E, Etot, cursor, colc);
    dinv_from_rowptr<<<cdiv(N, BLK), blk, 0, stream>>>(rowptr, dinv, N);
    grp_lb<<<cdiv(G_ + 1, BLK), blk, 0, stream>>>(batch, N, G_, gptr);

    // ================= GAT layer 1 (64 -> 512, all heads batched) ===========
    { dim3 g(4, cdiv(N, 128));
      gemm_mfma<unsigned short, false><<<g, blk, 0, stream>>>(
          xb, W1t, h1b, N, 64, 64, 64, 512); }
    attn_logits4<<<cdiv((long long)N * 4 * 64, BLK), blk, 0, stream>>>(
        h1b, a1s, a1d, als4, ald4, N);
    gat_gather4<<<cdiv((long long)N * 4 * 64, BLK), blk, 0, stream>>>(
        rowptr, colc, h1b, als4, ald4, accL, N);
    { dim3 g(1, YB); bn_part<512><<<g, blk, 0, stream>>>(accL, ps, pq, N, YB); }
    bn_reduce_fin<512><<<1, blk, 0, stream>>>(ps, pq, bn1g, bn1b, bsc, bsh, YB, 1.f / N);
    bn_apply_bf164<<<cdiv((long long)N * 128, BLK), blk, 0, stream>>>(
        accL, bsc, bsh, o1n, N * 128, 128, 512);

    // ======= GAT layer 2 (512 -> 4 heads x 256) + fused GCN GEMM ===========
    for (int hh = 0; hh < 4; ++hh) {
        { dim3 g(2, cdiv(N, 128));
          gemm_mfma<unsigned short, false><<<g, blk, 0, stream>>>(
              o1n, W2t + (size_t)hh * 256 * 512, hb, N, 512, 512, 512, 256); }
        attn_logits1<<<cdiv((long long)N * 64, BLK), blk, 0, stream>>>(
            hb, a2s + hh * 256, a2d + hh * 256, als4, ald4, N, 256);
        gat_gather256<<<cdiv((long long)N * 64, BLK), blk, 0, stream>>>(
            rowptr, colc, hb, als4, ald4, accA, N);
        { dim3 g(1, YB); bn_part<256><<<g, blk, 0, stream>>>(accA, ps, pq, N, YB); }
        bn_reduce_fin<256><<<1, blk, 0, stream>>>(ps, pq, bn2g + hh * 256, bn2b + hh * 256,
                                                  bsc, bsh, YB, 1.f / N);
        bn_apply_bf164<<<cdiv((long long)N * 64, BLK), blk, 0, stream>>>(
            accA, bsc, bsh, hb, N * 64, 64, 256);
        { dim3 g(2, cdiv(N, 128));
          if (hh == 0)
              gemm_mfma<float, false><<<g, blk, 0, stream>>>(
                  hb, Wgt + (size_t)hh * 256, h3acc, N, 256, 256, 1024, 256);
          else
              gemm_mfma<float, true><<<g, blk, 0, stream>>>(
                  hb, Wgt + (size_t)hh * 256, h3acc, N, 256, 256, 1024, 256); }
    }

    // ================= GCN aggregation + BN3 (apply folded into pooling) ====
    gcn_gather_f32<<<cdiv((long long)N * 64, BLK), blk, 0, stream>>>(
        rowptr, colc, h3acc, dinv, accA, N);
    { dim3 g(1, YB); bn_part<256><<<g, blk, 0, stream>>>(accA, ps, pq, N, YB); }
    bn_reduce_fin<256><<<1, blk, 0, stream>>>(ps, pq, bn3g, bn3b, bsc, bsh, YB, 1.f / N);

    // ================= Pooling (BN3 + relu fused) ===========================
    pool_gather_bn<<<G_, blk, 0, stream>>>(accA, bsc, bsh, gptr, z, G_);

    // solvent MLP -> z[:, 512:640]
    { dim3 g(2, cdiv(G_, 64));
      gemm_t<float, float, false, true><<<g, blk, 0, stream>>>(
          sfp, Wsm, bsm, z + 512, G_, 128, 128, 128, 128, 640); }

    // ================= Head (BNf apply folded into final_head) ==============
    { dim3 g(2, cdiv(G_, 64));
      gemm_t<float, float, false, false><<<g, blk, 0, stream>>>(
          z, Wf1, nullptr, f1, G_, 640, 128, 640, 128, 128); }
    { dim3 g(1, YB); bn_part<128><<<g, blk, 0, stream>>>(f1, ps, pq, G_, YB); }
    bn_reduce_fin<128><<<1, blk, 0, stream>>>(ps, pq, bnfg, bnfb, bsc, bsh, YB, 1.f / G_);
    final_head_bn<<<cdiv((long long)G_ * 64, BLK), blk, 0, stream>>>(
        f1, bsc, bsh, Wf2, bf2, outp, G_);
}